// Round 1
// baseline (1908.207 us; speedup 1.0000x reference)
//
#include <hip/hip_runtime.h>
#include <hip/hip_fp16.h>
#include <math.h>

// ---------------------------------------------------------------------------
// HolographicPatternExtractor  (B=16, C=1, H=W=512)
//  outputs (flat f32): sims[16,64] | spatial[16,1024] | phase_feats[16,3] | holo[16,128]
// ---------------------------------------------------------------------------

#define PI_F 3.14159274f          // float(np.pi)
#define TWO_PI_F 6.28318548f

// ---- workspace layout (dword offsets) ----
// region0: rowfft float2[16*512*512]  (8,388,608 dwords)  -- later aliased by grad[16][2][512][512]
// region1: magT float[16*512*512] (4,194,304 dwords) aliased by h1 half[16*32*256*256] (16,777,216 dwords)
// small:   sacc[16384] psum[16] psumsq[16] phist[1024 u32] mhist[65536 u32] dom[2048] comb[17456] out1[8192]
#define OFF_BIG   8388608
#define OFF_SMALL 25165824

// ===========================================================================
// zero init for accumulators (ws is poisoned 0xAA before every launch)
// ===========================================================================
__global__ void __launch_bounds__(256) zero_kernel(float* p, int n) {
    int i = blockIdx.x * 256 + threadIdx.x;
    if (i < n) p[i] = 0.0f;
}

// ===========================================================================
// FFT row pass: one 512-pt complex FFT per block (input real)
// ===========================================================================
__global__ void __launch_bounds__(256) fft_rows(const float* __restrict__ img,
                                                float2* __restrict__ rowfft) {
    __shared__ float2 s[512];
    __shared__ float2 tw[512];
    const int t = threadIdx.x;
    const int row = blockIdx.x;                 // b*512 + y
    const float* x = img + (long long)row * 512;

    for (int i = t; i < 512; i += 256) {
        if (i >= 1) {
            int h = 31 - __clz(i);
            int H = 1 << h;
            int p = i - H;
            float sn, cs;
            sincosf(-PI_F * (float)p / (float)H, &sn, &cs);
            tw[i] = make_float2(cs, sn);
        } else {
            tw[0] = make_float2(1.f, 0.f);
        }
    }
    for (int i = t; i < 512; i += 256) {
        int r = __brev((unsigned)i) >> 23;      // 9-bit reverse
        s[i] = make_float2(x[r], 0.f);
    }
    __syncthreads();
#pragma unroll
    for (int st = 1; st <= 9; ++st) {
        const int half = 1 << (st - 1);
        const int j = t;                        // 256 butterflies, one per thread
        const int pos = j & (half - 1);
        const int grp = j >> (st - 1);
        const int i1 = (grp << st) + pos;
        const int i2 = i1 + half;
        float2 w = tw[half + pos];
        float2 a = s[i1], b = s[i2];
        float tr = w.x * b.x - w.y * b.y;
        float ti = w.x * b.y + w.y * b.x;
        s[i1] = make_float2(a.x + tr, a.y + ti);
        s[i2] = make_float2(a.x - tr, a.y - ti);
        __syncthreads();
    }
    for (int i = t; i < 512; i += 256) rowfft[(long long)row * 512 + i] = s[i];
}

// ===========================================================================
// FFT column pass: 8 columns per block; fuse magnitude (transposed store) +
// phase statistics (sum, sumsq, 64-bin histogram)
// ===========================================================================
__global__ void __launch_bounds__(256) fft_cols(const float2* __restrict__ rowfft,
                                                float* __restrict__ magT,
                                                float* __restrict__ psum,
                                                float* __restrict__ psumsq,
                                                unsigned* __restrict__ phist) {
    __shared__ float2 s[8 * 512];               // column c contiguous at c*512
    __shared__ float2 tw[512];
    __shared__ unsigned ph[64];
    __shared__ float red[8];
    const int t = threadIdx.x;
    const int b = blockIdx.x >> 6;
    const int x0 = (blockIdx.x & 63) * 8;

    for (int i = t; i < 512; i += 256) {
        if (i >= 1) {
            int h = 31 - __clz(i);
            int H = 1 << h;
            int p = i - H;
            float sn, cs;
            sincosf(-PI_F * (float)p / (float)H, &sn, &cs);
            tw[i] = make_float2(cs, sn);
        } else {
            tw[0] = make_float2(1.f, 0.f);
        }
    }
    if (t < 64) ph[t] = 0u;
    for (int idx = t; idx < 8 * 512; idx += 256) {
        int y = idx >> 3;
        int c = idx & 7;
        int ry = __brev((unsigned)y) >> 23;
        s[c * 512 + ry] = rowfft[((long long)(b * 512 + y)) * 512 + x0 + c];
    }
    __syncthreads();

    const int c = t >> 5;                       // 8 columns x 32 threads
    const int j0 = t & 31;
    float2* sc = s + c * 512;
#pragma unroll
    for (int st = 1; st <= 9; ++st) {
        const int half = 1 << (st - 1);
#pragma unroll
        for (int k = 0; k < 8; ++k) {
            int j = j0 + (k << 5);
            int pos = j & (half - 1);
            int grp = j >> (st - 1);
            int i1 = (grp << st) + pos;
            int i2 = i1 + half;
            float2 w = tw[half + pos];
            float2 a = sc[i1], bb = sc[i2];
            float tr = w.x * bb.x - w.y * bb.y;
            float ti = w.x * bb.y + w.y * bb.x;
            sc[i1] = make_float2(a.x + tr, a.y + ti);
            sc[i2] = make_float2(a.x - tr, a.y - ti);
        }
        __syncthreads();
    }

    float lsum = 0.f, lsq = 0.f;
    for (int idx = t; idx < 8 * 512; idx += 256) {
        int cc = idx >> 9;
        int y = idx & 511;
        float2 v = s[cc * 512 + y];
        float mag = sqrtf(v.x * v.x + v.y * v.y);
        magT[((long long)(b * 512 + x0 + cc)) * 512 + y] = mag;
        float phv = atan2f(v.y, v.x);
        lsum += phv;
        lsq += phv * phv;
        int bin = (int)floorf((phv + PI_F) / TWO_PI_F * 64.0f);
        bin = min(max(bin, 0), 63);
        atomicAdd(&ph[bin], 1u);
    }
    for (int off = 32; off > 0; off >>= 1) {
        lsum += __shfl_down(lsum, off);
        lsq  += __shfl_down(lsq, off);
    }
    if ((t & 63) == 0) { red[t >> 6] = lsum; red[4 + (t >> 6)] = lsq; }
    __syncthreads();
    if (t == 0) {
        atomicAdd(psum + b,   red[0] + red[1] + red[2] + red[3]);
        atomicAdd(psumsq + b, red[4] + red[5] + red[6] + red[7]);
    }
    if (t < 64 && ph[t]) atomicAdd(&phist[b * 64 + t], ph[t]);
}

// ===========================================================================
// magnitude histogram for top-k threshold (bits>>19 is monotone for mag>=0)
// ===========================================================================
__global__ void __launch_bounds__(256) mag_hist(const float* __restrict__ magT,
                                                unsigned* __restrict__ mhist) {
    __shared__ unsigned h[4096];
    for (int i = threadIdx.x; i < 4096; i += 256) h[i] = 0u;
    __syncthreads();
    int b = blockIdx.x >> 4;
    int chunk = blockIdx.x & 15;
    const float* m = magT + (long long)b * 262144 + chunk * 16384;
    for (int i = threadIdx.x; i < 16384; i += 256) {
        unsigned bits = __float_as_uint(m[i]);
        unsigned bin = min(bits >> 19, 4095u);
        atomicAdd(&h[bin], 1u);
    }
    __syncthreads();
    for (int i = threadIdx.x; i < 4096; i += 256)
        if (h[i]) atomicAdd(&mhist[b * 4096 + i], h[i]);
}

// ===========================================================================
// top-k select + bitonic sort descending -> dom[b][128]
// ===========================================================================
#define TK_CAP 4096
__global__ void __launch_bounds__(256) topk_sort(const float* __restrict__ magT,
                                                 const unsigned* __restrict__ mhist,
                                                 float* __restrict__ dom) {
    __shared__ unsigned h[4096];
    __shared__ float cand[TK_CAP];
    __shared__ int sel_bin;
    __shared__ unsigned cnt;
    const int b = blockIdx.x;
    const int t = threadIdx.x;
    for (int i = t; i < 4096; i += 256) h[i] = mhist[b * 4096 + i];
    for (int i = t; i < TK_CAP; i += 256) cand[i] = -1.0f;
    if (t == 0) cnt = 0u;
    __syncthreads();
    if (t == 0) {
        unsigned acc = 0; int tbin = 0;
        for (int i = 4095; i >= 0; --i) {
            acc += h[i];
            if (acc >= 128u) { tbin = i; break; }
        }
        sel_bin = tbin;
    }
    __syncthreads();
    const unsigned tb = (unsigned)sel_bin;
    const float* m = magT + (long long)b * 262144;
    for (int i = t; i < 262144; i += 256) {
        float v = m[i];
        unsigned bin = min(__float_as_uint(v) >> 19, 4095u);
        if (bin >= tb) {
            unsigned p = atomicAdd(&cnt, 1u);
            if (p < TK_CAP) cand[p] = v;
        }
    }
    __syncthreads();
    // bitonic sort, descending
    for (int k = 2; k <= TK_CAP; k <<= 1) {
        for (int j = k >> 1; j > 0; j >>= 1) {
            for (int i = t; i < TK_CAP; i += 256) {
                int ixj = i ^ j;
                if (ixj > i) {
                    float a = cand[i], c2 = cand[ixj];
                    bool up = ((i & k) == 0);
                    if (up ? (a < c2) : (a > c2)) { cand[i] = c2; cand[ixj] = a; }
                }
            }
            __syncthreads();
        }
    }
    if (t < 128) dom[b * 128 + t] = cand[t];
}

// ===========================================================================
// sims = normalize(dom) @ normalize(receptors)^T   -> d_out + combined
// ===========================================================================
__global__ void __launch_bounds__(256) sims_kernel(const float* __restrict__ dom,
                                                   const float* __restrict__ rec,
                                                   float* __restrict__ comb,
                                                   float* __restrict__ dout) {
    __shared__ float sd[16 * 128];
    __shared__ float sr[64 * 128];
    __shared__ float scale[80];
    const int t = threadIdx.x;
    for (int i = t; i < 2048; i += 256) sd[i] = dom[i];
    for (int i = t; i < 8192; i += 256) sr[i] = rec[i];
    __syncthreads();
    if (t < 80) {
        const float* base = (t < 16) ? (sd + t * 128) : (sr + (t - 16) * 128);
        float s = 0.f;
        for (int k = 0; k < 128; ++k) s += base[k] * base[k];
        scale[t] = 1.0f / fmaxf(sqrtf(s), 1e-12f);
    }
    __syncthreads();
    for (int o = t; o < 1024; o += 256) {
        int b = o >> 6, p = o & 63;
        const float* dv = sd + b * 128;
        const float* rv = sr + p * 128;
        float s = 0.f;
        for (int k = 0; k < 128; ++k) s += dv[k] * rv[k];
        float val = s * scale[b] * scale[16 + p];
        dout[b * 64 + p] = val;
        comb[b * 1091 + p] = val;
    }
}

// ===========================================================================
// gradients: gmag / gori  (jnp.gradient semantics: central, one-sided edges)
// ===========================================================================
__global__ void __launch_bounds__(256) grad_kernel(const float* __restrict__ img,
                                                   float* __restrict__ grad) {
    int idx = blockIdx.x * 256 + threadIdx.x;     // 16*262144
    int b = idx >> 18;
    int r = idx & 262143;
    int y = r >> 9, x = r & 511;
    const float* im = img + (long long)b * 262144;
    int yp = min(y + 1, 511), ym = max(y - 1, 0);
    int xp = min(x + 1, 511), xm = max(x - 1, 0);
    float fy = (y == 0 || y == 511) ? 1.f : 0.5f;
    float fx = (x == 0 || x == 511) ? 1.f : 0.5f;
    float gy = (im[yp * 512 + x] - im[ym * 512 + x]) * fy;
    float gx = (im[y * 512 + xp] - im[y * 512 + xm]) * fx;
    grad[((long long)(b * 2)) * 262144 + r]     = sqrtf(gx * gx + gy * gy);
    grad[((long long)(b * 2 + 1)) * 262144 + r] = atan2f(gy, gx);
}

// ===========================================================================
// conv1 (2->32, 3x3 SAME) + ReLU + maxpool2 -> h1 (fp16)
// one thread per pooled pixel; all 32 oc; weights via uniform scalar loads
// ===========================================================================
__global__ void __launch_bounds__(256) conv1_pool(const float* __restrict__ grad,
                                                  const float* __restrict__ w1,
                                                  const float* __restrict__ c1b,
                                                  __half* __restrict__ h1) {
    int idx = blockIdx.x * 256 + threadIdx.x;     // 16*65536
    int b = idx >> 16;
    int r = idx & 65535;
    int py = r >> 8, px = r & 255;
    int y0 = 2 * py - 1, x0 = 2 * px - 1;
    float in[2][4][4];
#pragma unroll
    for (int ic = 0; ic < 2; ++ic) {
        const float* g = grad + ((long long)(b * 2 + ic)) * 262144;
#pragma unroll
        for (int dy = 0; dy < 4; ++dy) {
            int gy = y0 + dy;
            bool oky = (unsigned)gy < 512u;
#pragma unroll
            for (int dx = 0; dx < 4; ++dx) {
                int gx = x0 + dx;
                in[ic][dy][dx] = (oky && (unsigned)gx < 512u) ? g[gy * 512 + gx] : 0.f;
            }
        }
    }
#pragma unroll 4
    for (int oc = 0; oc < 32; ++oc) {
        float wv[18];
#pragma unroll
        for (int i = 0; i < 18; ++i) wv[i] = w1[oc * 18 + i];
        float bias = c1b[oc];
        float mx = -3.4e38f;
#pragma unroll
        for (int yy = 0; yy < 2; ++yy)
#pragma unroll
            for (int xx = 0; xx < 2; ++xx) {
                float acc = bias;
#pragma unroll
                for (int ic = 0; ic < 2; ++ic)
#pragma unroll
                    for (int ky = 0; ky < 3; ++ky)
#pragma unroll
                        for (int kx = 0; kx < 3; ++kx)
                            acc += wv[(ic * 3 + ky) * 3 + kx] * in[ic][yy + ky][xx + kx];
                mx = fmaxf(mx, acc);
            }
        h1[((long long)(b * 32 + oc)) * 65536 + py * 256 + px] = __float2half(fmaxf(mx, 0.f));
    }
}

// ===========================================================================
// conv2 (32->64, 3x3 SAME) + ReLU + 64x64 average pool (accumulate partials)
// block = 16x16 output tile; 4 chunks of 16 oc; input tile staged in LDS
// ===========================================================================
__global__ void __launch_bounds__(256) conv2_pool(const __half* __restrict__ h1,
                                                  const float* __restrict__ w2,
                                                  const float* __restrict__ c2b,
                                                  float* __restrict__ sacc) {
    __shared__ float tile[32][18][18];
    __shared__ float lsum[64];
    const int blk = blockIdx.x;                   // 16 b * 256 tiles
    const int b = blk >> 8;
    const int tr = blk & 255;
    const int ty0 = (tr >> 4) * 16, tx0 = (tr & 15) * 16;
    const int t = threadIdx.x;
    if (t < 64) lsum[t] = 0.f;
    for (int idx = t; idx < 32 * 18 * 18; idx += 256) {
        int ic = idx / 324;
        int rem = idx - ic * 324;
        int iy = rem / 18, ix = rem - iy * 18;
        int gy = ty0 - 1 + iy, gx = tx0 - 1 + ix;
        float v = 0.f;
        if ((unsigned)gy < 256u && (unsigned)gx < 256u)
            v = __half2float(h1[((long long)(b * 32 + ic)) * 65536 + gy * 256 + gx]);
        tile[ic][iy][ix] = v;
    }
    __syncthreads();
    const int ty = t >> 4, tx = t & 15;
    const int cell = ((ty0 >> 6) << 2) + (tx0 >> 6);
#pragma unroll 1
    for (int chunk = 0; chunk < 4; ++chunk) {
        const int oc0 = chunk << 4;
        float acc[16];
#pragma unroll
        for (int o = 0; o < 16; ++o) acc[o] = c2b[oc0 + o];
#pragma unroll 1
        for (int ic = 0; ic < 32; ++ic) {
            float rg[9];
#pragma unroll
            for (int ky = 0; ky < 3; ++ky)
#pragma unroll
                for (int kx = 0; kx < 3; ++kx)
                    rg[ky * 3 + kx] = tile[ic][ty + ky][tx + kx];
            const float* wbase = w2 + (oc0 * 32 + ic) * 9;
#pragma unroll
            for (int o = 0; o < 16; ++o) {
                const float* wr = wbase + o * 288;     // o*32*9
#pragma unroll
                for (int k = 0; k < 9; ++k) acc[o] += wr[k] * rg[k];
            }
        }
#pragma unroll
        for (int o = 0; o < 16; ++o) {
            float v = fmaxf(acc[o], 0.f);
            for (int off = 32; off > 0; off >>= 1) v += __shfl_down(v, off);
            if ((t & 63) == 0) atomicAdd(&lsum[oc0 + o], v);
        }
    }
    __syncthreads();
    if (t < 64) atomicAdd(&sacc[((b << 6) + t) * 16 + cell], lsum[t]);
}

// ===========================================================================
// phase feature finalize
// ===========================================================================
__global__ void __launch_bounds__(64) finalize_phase(const float* __restrict__ psum,
                                                     const float* __restrict__ psumsq,
                                                     const unsigned* __restrict__ phist,
                                                     float* __restrict__ comb,
                                                     float* __restrict__ dout) {
    int t = threadIdx.x;
    if (t < 16) {
        const float N = 262144.f;
        float s = psum[t];
        float mean = s / N;
        float var = (psumsq[t] - s * s / N) / (N - 1.f);
        float sd = sqrtf(fmaxf(var, 0.f));
        float ent = 0.f;
        for (int i = 0; i < 64; ++i) {
            float p = (float)phist[t * 64 + i] / N;
            ent -= p * logf(p + 1e-10f);
        }
        dout[17408 + t * 3 + 0] = mean;
        dout[17408 + t * 3 + 1] = sd;
        dout[17408 + t * 3 + 2] = ent;
        float* cb = comb + t * 1091 + 1088;
        cb[0] = mean; cb[1] = sd; cb[2] = ent;
    }
}

// ===========================================================================
// spatial finalize: /4096 -> d_out + combined
// ===========================================================================
__global__ void __launch_bounds__(256) finalize_spatial(const float* __restrict__ sacc,
                                                        float* __restrict__ comb,
                                                        float* __restrict__ dout) {
    int idx = blockIdx.x * 256 + threadIdx.x;     // 16384
    int b = idx >> 10, j = idx & 1023;
    float v = sacc[idx] * (1.0f / 4096.0f);
    dout[1024 + idx] = v;
    comb[b * 1091 + 64 + j] = v;
}

// ===========================================================================
// fc1: [16,1091] -> relu -> [16,512]
// ===========================================================================
__global__ void __launch_bounds__(256) fc1_kernel(const float* __restrict__ comb,
                                                  const float* __restrict__ W1,
                                                  const float* __restrict__ B1,
                                                  float* __restrict__ out1) {
    __shared__ float c[1091];
    const int blk = blockIdx.x;                   // 32 blocks
    const int bb = blk >> 1;
    const int o = ((blk & 1) << 8) + threadIdx.x;
    for (int i = threadIdx.x; i < 1091; i += 256) c[i] = comb[bb * 1091 + i];
    __syncthreads();
    const float* w = W1 + (long long)o * 1091;
    float acc = B1[o];
#pragma unroll 4
    for (int k = 0; k < 1091; ++k) acc += c[k] * w[k];
    out1[(bb << 9) + o] = fmaxf(acc, 0.f);
}

// ===========================================================================
// fc2 + layernorm -> holo
// ===========================================================================
__global__ void __launch_bounds__(128) fc2_ln(const float* __restrict__ out1,
                                              const float* __restrict__ W2,
                                              const float* __restrict__ B2,
                                              const float* __restrict__ g,
                                              const float* __restrict__ beta,
                                              float* __restrict__ dout) {
    __shared__ float c[512];
    __shared__ float red[4];
    const int b = blockIdx.x, t = threadIdx.x;
    for (int i = t; i < 512; i += 128) c[i] = out1[b * 512 + i];
    __syncthreads();
    const float* w = W2 + t * 512;
    float acc = B2[t];
#pragma unroll 4
    for (int k = 0; k < 512; ++k) acc += c[k] * w[k];
    float s = acc;
    for (int off = 32; off > 0; off >>= 1) s += __shfl_down(s, off);
    if ((t & 63) == 0) red[t >> 6] = s;
    __syncthreads();
    float mu = (red[0] + red[1]) * (1.0f / 128.0f);
    float d = acc - mu;
    float q = d * d;
    for (int off = 32; off > 0; off >>= 1) q += __shfl_down(q, off);
    if ((t & 63) == 0) red[2 + (t >> 6)] = q;
    __syncthreads();
    float var = (red[2] + red[3]) * (1.0f / 128.0f);
    dout[17456 + b * 128 + t] = d / sqrtf(var + 1e-5f) * g[t] + beta[t];
}

// ===========================================================================
// launcher
// ===========================================================================
extern "C" void kernel_launch(void* const* d_in, const int* in_sizes, int n_in,
                              void* d_out, int out_size, void* d_ws, size_t ws_size,
                              hipStream_t stream) {
    const float* img = (const float*)d_in[0];
    const float* rec = (const float*)d_in[1];
    const float* w1  = (const float*)d_in[2];
    const float* c1b = (const float*)d_in[3];
    const float* w2  = (const float*)d_in[4];
    const float* c2b = (const float*)d_in[5];
    const float* fw1 = (const float*)d_in[6];
    const float* fb1 = (const float*)d_in[7];
    const float* fw2 = (const float*)d_in[8];
    const float* fb2 = (const float*)d_in[9];
    const float* lng = (const float*)d_in[10];
    const float* lnb = (const float*)d_in[11];
    float* out = (float*)d_out;

    float* ws = (float*)d_ws;
    float2* rowfft = (float2*)ws;                 // region0 (later grad)
    float* grad    = ws;                          // alias (rowfft dead after fft_cols)
    float* magT    = ws + OFF_BIG;                // region1
    __half* h1     = (__half*)(ws + OFF_BIG);     // alias (magT dead after topk)
    float* small_  = ws + OFF_SMALL;
    float* sacc    = small_;                      // 16384
    float* psum    = small_ + 16384;              // 16
    float* psumsq  = small_ + 16400;              // 16
    unsigned* phist = (unsigned*)(small_ + 16416);// 1024
    unsigned* mhist = (unsigned*)(small_ + 17440);// 65536
    float* dom     = small_ + 82976;              // 2048
    float* comb    = small_ + 85024;              // 17456
    float* out1    = small_ + 102480;             // 8192

    zero_kernel<<<325, 256, 0, stream>>>(sacc, 82976);
    fft_rows<<<8192, 256, 0, stream>>>(img, rowfft);
    fft_cols<<<1024, 256, 0, stream>>>(rowfft, magT, psum, psumsq, phist);
    mag_hist<<<256, 256, 0, stream>>>(magT, mhist);
    topk_sort<<<16, 256, 0, stream>>>(magT, mhist, dom);
    sims_kernel<<<1, 256, 0, stream>>>(dom, rec, comb, out);
    grad_kernel<<<16384, 256, 0, stream>>>(img, grad);
    conv1_pool<<<4096, 256, 0, stream>>>(grad, w1, c1b, h1);
    conv2_pool<<<4096, 256, 0, stream>>>(h1, w2, c2b, sacc);
    finalize_phase<<<1, 64, 0, stream>>>(psum, psumsq, phist, comb, out);
    finalize_spatial<<<64, 256, 0, stream>>>(sacc, comb, out);
    fc1_kernel<<<32, 256, 0, stream>>>(comb, fw1, fb1, out1);
    fc2_ln<<<16, 128, 0, stream>>>(out1, fw2, fb2, lng, lnb, out);
}

// Round 2
// 1059.928 us; speedup vs baseline: 1.8003x; 1.8003x over previous
//
#include <hip/hip_runtime.h>
#include <hip/hip_fp16.h>
#include <math.h>

// ---------------------------------------------------------------------------
// HolographicPatternExtractor  (B=16, C=1, H=W=512)
//  outputs (flat f32): sims[16,64] | spatial[16,1024] | phase_feats[16,3] | holo[16,128]
// ---------------------------------------------------------------------------

#define PI_F 3.14159274f          // float(np.pi)
#define TWO_PI_F 6.28318548f

typedef _Float16 half8 __attribute__((ext_vector_type(8)));
typedef float floatx4 __attribute__((ext_vector_type(4)));

// ---- workspace layout (dword offsets) ----
// region0: rowfft float2[16*512*512]  (8,388,608 dwords)  -- later aliased by grad[16][2][512][512]
// region1: magT float[16*512*512] (4,194,304 dwords) aliased by h1 NHWC half[16*256*256*32] (16,777,216 dwords)
#define OFF_BIG   8388608
#define OFF_SMALL 25165824

// ===========================================================================
__global__ void __launch_bounds__(256) zero_kernel(float* p, int n) {
    int i = blockIdx.x * 256 + threadIdx.x;
    if (i < n) p[i] = 0.0f;
}

// ===========================================================================
// FFT row pass: one 512-pt complex FFT per block (input real)
// ===========================================================================
__global__ void __launch_bounds__(256) fft_rows(const float* __restrict__ img,
                                                float2* __restrict__ rowfft) {
    __shared__ float2 s[512];
    __shared__ float2 tw[512];
    const int t = threadIdx.x;
    const int row = blockIdx.x;                 // b*512 + y
    const float* x = img + (long long)row * 512;

    for (int i = t; i < 512; i += 256) {
        if (i >= 1) {
            int h = 31 - __clz(i);
            int H = 1 << h;
            int p = i - H;
            float sn, cs;
            sincosf(-PI_F * (float)p / (float)H, &sn, &cs);
            tw[i] = make_float2(cs, sn);
        } else {
            tw[0] = make_float2(1.f, 0.f);
        }
    }
    for (int i = t; i < 512; i += 256) {
        int r = __brev((unsigned)i) >> 23;      // 9-bit reverse
        s[i] = make_float2(x[r], 0.f);
    }
    __syncthreads();
#pragma unroll
    for (int st = 1; st <= 9; ++st) {
        const int half = 1 << (st - 1);
        const int j = t;                        // 256 butterflies, one per thread
        const int pos = j & (half - 1);
        const int grp = j >> (st - 1);
        const int i1 = (grp << st) + pos;
        const int i2 = i1 + half;
        float2 w = tw[half + pos];
        float2 a = s[i1], b = s[i2];
        float tr = w.x * b.x - w.y * b.y;
        float ti = w.x * b.y + w.y * b.x;
        s[i1] = make_float2(a.x + tr, a.y + ti);
        s[i2] = make_float2(a.x - tr, a.y - ti);
        __syncthreads();
    }
    for (int i = t; i < 512; i += 256) rowfft[(long long)row * 512 + i] = s[i];
}

// ===========================================================================
// FFT column pass: 8 columns per block; fuse magnitude (transposed store) +
// phase statistics (sum, sumsq, 64-bin histogram)
// ===========================================================================
__global__ void __launch_bounds__(256) fft_cols(const float2* __restrict__ rowfft,
                                                float* __restrict__ magT,
                                                float* __restrict__ psum,
                                                float* __restrict__ psumsq,
                                                unsigned* __restrict__ phist) {
    __shared__ float2 s[8 * 512];               // column c contiguous at c*512
    __shared__ float2 tw[512];
    __shared__ unsigned ph[64];
    __shared__ float red[8];
    const int t = threadIdx.x;
    const int b = blockIdx.x >> 6;
    const int x0 = (blockIdx.x & 63) * 8;

    for (int i = t; i < 512; i += 256) {
        if (i >= 1) {
            int h = 31 - __clz(i);
            int H = 1 << h;
            int p = i - H;
            float sn, cs;
            sincosf(-PI_F * (float)p / (float)H, &sn, &cs);
            tw[i] = make_float2(cs, sn);
        } else {
            tw[0] = make_float2(1.f, 0.f);
        }
    }
    if (t < 64) ph[t] = 0u;
    for (int idx = t; idx < 8 * 512; idx += 256) {
        int y = idx >> 3;
        int c = idx & 7;
        int ry = __brev((unsigned)y) >> 23;
        s[c * 512 + ry] = rowfft[((long long)(b * 512 + y)) * 512 + x0 + c];
    }
    __syncthreads();

    const int c = t >> 5;                       // 8 columns x 32 threads
    const int j0 = t & 31;
    float2* sc = s + c * 512;
#pragma unroll
    for (int st = 1; st <= 9; ++st) {
        const int half = 1 << (st - 1);
#pragma unroll
        for (int k = 0; k < 8; ++k) {
            int j = j0 + (k << 5);
            int pos = j & (half - 1);
            int grp = j >> (st - 1);
            int i1 = (grp << st) + pos;
            int i2 = i1 + half;
            float2 w = tw[half + pos];
            float2 a = sc[i1], bb = sc[i2];
            float tr = w.x * bb.x - w.y * bb.y;
            float ti = w.x * bb.y + w.y * bb.x;
            sc[i1] = make_float2(a.x + tr, a.y + ti);
            sc[i2] = make_float2(a.x - tr, a.y - ti);
        }
        __syncthreads();
    }

    float lsum = 0.f, lsq = 0.f;
    for (int idx = t; idx < 8 * 512; idx += 256) {
        int cc = idx >> 9;
        int y = idx & 511;
        float2 v = s[cc * 512 + y];
        float mag = sqrtf(v.x * v.x + v.y * v.y);
        magT[((long long)(b * 512 + x0 + cc)) * 512 + y] = mag;
        float phv = atan2f(v.y, v.x);
        lsum += phv;
        lsq += phv * phv;
        int bin = (int)floorf((phv + PI_F) / TWO_PI_F * 64.0f);
        bin = min(max(bin, 0), 63);
        atomicAdd(&ph[bin], 1u);
    }
    for (int off = 32; off > 0; off >>= 1) {
        lsum += __shfl_down(lsum, off);
        lsq  += __shfl_down(lsq, off);
    }
    if ((t & 63) == 0) { red[t >> 6] = lsum; red[4 + (t >> 6)] = lsq; }
    __syncthreads();
    if (t == 0) {
        atomicAdd(psum + b,   red[0] + red[1] + red[2] + red[3]);
        atomicAdd(psumsq + b, red[4] + red[5] + red[6] + red[7]);
    }
    if (t < 64 && ph[t]) atomicAdd(&phist[b * 64 + t], ph[t]);
}

// ===========================================================================
// magnitude histogram for top-k threshold
// ===========================================================================
__global__ void __launch_bounds__(256) mag_hist(const float* __restrict__ magT,
                                                unsigned* __restrict__ mhist) {
    __shared__ unsigned h[4096];
    for (int i = threadIdx.x; i < 4096; i += 256) h[i] = 0u;
    __syncthreads();
    int b = blockIdx.x >> 4;
    int chunk = blockIdx.x & 15;
    const float* m = magT + (long long)b * 262144 + chunk * 16384;
    for (int i = threadIdx.x; i < 16384; i += 256) {
        unsigned bits = __float_as_uint(m[i]);
        unsigned bin = min(bits >> 19, 4095u);
        atomicAdd(&h[bin], 1u);
    }
    __syncthreads();
    for (int i = threadIdx.x; i < 4096; i += 256)
        if (h[i]) atomicAdd(&mhist[b * 4096 + i], h[i]);
}

// ===========================================================================
// top-k select + bitonic sort descending -> dom[b][128]
// ===========================================================================
#define TK_CAP 4096
__global__ void __launch_bounds__(256) topk_sort(const float* __restrict__ magT,
                                                 const unsigned* __restrict__ mhist,
                                                 float* __restrict__ dom) {
    __shared__ unsigned h[4096];
    __shared__ float cand[TK_CAP];
    __shared__ int sel_bin;
    __shared__ unsigned cnt;
    const int b = blockIdx.x;
    const int t = threadIdx.x;
    for (int i = t; i < 4096; i += 256) h[i] = mhist[b * 4096 + i];
    for (int i = t; i < TK_CAP; i += 256) cand[i] = -1.0f;
    if (t == 0) cnt = 0u;
    __syncthreads();
    if (t == 0) {
        unsigned acc = 0; int tbin = 0;
        for (int i = 4095; i >= 0; --i) {
            acc += h[i];
            if (acc >= 128u) { tbin = i; break; }
        }
        sel_bin = tbin;
    }
    __syncthreads();
    const unsigned tb = (unsigned)sel_bin;
    const float* m = magT + (long long)b * 262144;
    for (int i = t; i < 262144; i += 256) {
        float v = m[i];
        unsigned bin = min(__float_as_uint(v) >> 19, 4095u);
        if (bin >= tb) {
            unsigned p = atomicAdd(&cnt, 1u);
            if (p < TK_CAP) cand[p] = v;
        }
    }
    __syncthreads();
    for (int k = 2; k <= TK_CAP; k <<= 1) {
        for (int j = k >> 1; j > 0; j >>= 1) {
            for (int i = t; i < TK_CAP; i += 256) {
                int ixj = i ^ j;
                if (ixj > i) {
                    float a = cand[i], c2 = cand[ixj];
                    bool up = ((i & k) == 0);
                    if (up ? (a < c2) : (a > c2)) { cand[i] = c2; cand[ixj] = a; }
                }
            }
            __syncthreads();
        }
    }
    if (t < 128) dom[b * 128 + t] = cand[t];
}

// ===========================================================================
// sims = normalize(dom) @ normalize(receptors)^T
// ===========================================================================
__global__ void __launch_bounds__(256) sims_kernel(const float* __restrict__ dom,
                                                   const float* __restrict__ rec,
                                                   float* __restrict__ comb,
                                                   float* __restrict__ dout) {
    __shared__ float sd[16 * 128];
    __shared__ float sr[64 * 128];
    __shared__ float scale[80];
    const int t = threadIdx.x;
    for (int i = t; i < 2048; i += 256) sd[i] = dom[i];
    for (int i = t; i < 8192; i += 256) sr[i] = rec[i];
    __syncthreads();
    if (t < 80) {
        const float* base = (t < 16) ? (sd + t * 128) : (sr + (t - 16) * 128);
        float s = 0.f;
        for (int k = 0; k < 128; ++k) s += base[k] * base[k];
        scale[t] = 1.0f / fmaxf(sqrtf(s), 1e-12f);
    }
    __syncthreads();
    for (int o = t; o < 1024; o += 256) {
        int b = o >> 6, p = o & 63;
        const float* dv = sd + b * 128;
        const float* rv = sr + p * 128;
        float s = 0.f;
        for (int k = 0; k < 128; ++k) s += dv[k] * rv[k];
        float val = s * scale[b] * scale[16 + p];
        dout[b * 64 + p] = val;
        comb[b * 1091 + p] = val;
    }
}

// ===========================================================================
// gradients: gmag / gori
// ===========================================================================
__global__ void __launch_bounds__(256) grad_kernel(const float* __restrict__ img,
                                                   float* __restrict__ grad) {
    int idx = blockIdx.x * 256 + threadIdx.x;     // 16*262144
    int b = idx >> 18;
    int r = idx & 262143;
    int y = r >> 9, x = r & 511;
    const float* im = img + (long long)b * 262144;
    int yp = min(y + 1, 511), ym = max(y - 1, 0);
    int xp = min(x + 1, 511), xm = max(x - 1, 0);
    float fy = (y == 0 || y == 511) ? 1.f : 0.5f;
    float fx = (x == 0 || x == 511) ? 1.f : 0.5f;
    float gy = (im[yp * 512 + x] - im[ym * 512 + x]) * fy;
    float gx = (im[y * 512 + xp] - im[y * 512 + xm]) * fx;
    grad[((long long)(b * 2)) * 262144 + r]     = sqrtf(gx * gx + gy * gy);
    grad[((long long)(b * 2 + 1)) * 262144 + r] = atan2f(gy, gx);
}

// ===========================================================================
// conv1 (2->32, 3x3 SAME) + ReLU + maxpool2 -> h1 NHWC fp16 [b][y][x][ic=32]
// ===========================================================================
__global__ void __launch_bounds__(256) conv1_pool(const float* __restrict__ grad,
                                                  const float* __restrict__ w1,
                                                  const float* __restrict__ c1b,
                                                  _Float16* __restrict__ h1) {
    int idx = blockIdx.x * 256 + threadIdx.x;     // 16*65536
    int b = idx >> 16;
    int r = idx & 65535;
    int py = r >> 8, px = r & 255;
    int y0 = 2 * py - 1, x0 = 2 * px - 1;
    float in[2][4][4];
#pragma unroll
    for (int ic = 0; ic < 2; ++ic) {
        const float* g = grad + ((long long)(b * 2 + ic)) * 262144;
#pragma unroll
        for (int dy = 0; dy < 4; ++dy) {
            int gy = y0 + dy;
            bool oky = (unsigned)gy < 512u;
#pragma unroll
            for (int dx = 0; dx < 4; ++dx) {
                int gx = x0 + dx;
                in[ic][dy][dx] = (oky && (unsigned)gx < 512u) ? g[gy * 512 + gx] : 0.f;
            }
        }
    }
    union { _Float16 h[32]; floatx4 v[4]; } outp;
#pragma unroll 4
    for (int oc = 0; oc < 32; ++oc) {
        float wv[18];
#pragma unroll
        for (int i = 0; i < 18; ++i) wv[i] = w1[oc * 18 + i];
        float bias = c1b[oc];
        float mx = -3.4e38f;
#pragma unroll
        for (int yy = 0; yy < 2; ++yy)
#pragma unroll
            for (int xx = 0; xx < 2; ++xx) {
                float acc = bias;
#pragma unroll
                for (int ic = 0; ic < 2; ++ic)
#pragma unroll
                    for (int ky = 0; ky < 3; ++ky)
#pragma unroll
                        for (int kx = 0; kx < 3; ++kx)
                            acc += wv[(ic * 3 + ky) * 3 + kx] * in[ic][yy + ky][xx + kx];
                mx = fmaxf(mx, acc);
            }
        outp.h[oc] = (_Float16)fmaxf(mx, 0.f);
    }
    floatx4* dst = (floatx4*)(h1 + ((size_t)idx) * 32);
#pragma unroll
    for (int c = 0; c < 4; ++c) dst[c] = outp.v[c];
}

// ===========================================================================
// weight repack for conv2 MFMA: wrep[tap][nt][lane][j] = w2[oc][ic][tap]
//   oc = nt*16 + (lane&15), ic = (lane>>4)*8 + j
// ===========================================================================
__global__ void __launch_bounds__(256) wrepack_kernel(const float* __restrict__ w2,
                                                      _Float16* __restrict__ wrep) {
    int idx = blockIdx.x * 256 + threadIdx.x;   // 18432
    if (idx < 18432) {
        int j = idx & 7;
        int lane = (idx >> 3) & 63;
        int nt = (idx >> 9) & 3;
        int tap = idx >> 11;
        int oc = nt * 16 + (lane & 15);
        int ic = (lane >> 4) * 8 + j;
        wrep[idx] = (_Float16)w2[(oc * 32 + ic) * 9 + tap];
    }
}

// ===========================================================================
// conv2 (32->64, 3x3 SAME) + ReLU + 64x64 avg-pool partials — implicit GEMM
// via mfma_f32_16x16x32_f16.  Block = 16 rows x 32 px tile; 4 waves x 4 rows.
// A-frag: lane m=px&15, k=ic (quad*8+j)  <- ds_read_b128 from NHWC LDS tile
// B-frag: pre-swizzled weights, coalesced 16B global loads
// ===========================================================================
__global__ void __launch_bounds__(256) conv2_mfma(const _Float16* __restrict__ h1,
                                                  const half8* __restrict__ wrep,
                                                  const float* __restrict__ c2b,
                                                  float* __restrict__ sacc) {
    __shared__ _Float16 tile[18 * 34 * 32];     // [row][px][ic] 39,168 B
    __shared__ float lsum[64];
    const int blk = blockIdx.x;                 // b*128 + yt*8 + xt
    const int b  = blk >> 7;
    const int yt = (blk >> 3) & 15;
    const int xt = blk & 7;
    const int y0 = yt * 16, x0 = xt * 32;
    const int t = threadIdx.x;
    if (t < 64) lsum[t] = 0.f;

    // ---- stage input halo tile: rows y0-1..y0+16, px x0-1..x0+32, NHWC ----
    for (int c = t; c < 18 * 136; c += 256) {   // 136 x 16B chunks per row
        int row = c / 136;
        int chunk = c - row * 136;
        int gy = y0 - 1 + row;
        int px = chunk >> 2;
        int gx = x0 - 1 + px;
        floatx4 v = {0.f, 0.f, 0.f, 0.f};
        if ((unsigned)gy < 256u && (unsigned)gx < 256u)
            v = *(const floatx4*)(h1 + (((size_t)(b * 256 + gy)) * 256 + gx) * 32 + (chunk & 3) * 8);
        *(floatx4*)(tile + (row * 34 + px) * 32 + (chunk & 3) * 8) = v;
    }
    __syncthreads();

    const int w = t >> 6, lane = t & 63;
    const int q = lane >> 4, ln15 = lane & 15;
    float bias[4];
#pragma unroll
    for (int nt = 0; nt < 4; ++nt) bias[nt] = c2b[nt * 16 + ln15];
    float partial[4] = {0.f, 0.f, 0.f, 0.f};

#pragma unroll 1
    for (int gr = 0; gr < 2; ++gr) {
        floatx4 acc[4][4];
#pragma unroll
        for (int mt = 0; mt < 4; ++mt)
#pragma unroll
            for (int nt = 0; nt < 4; ++nt)
                acc[mt][nt] = floatx4{bias[nt], bias[nt], bias[nt], bias[nt]};
#pragma unroll 1
        for (int tap = 0; tap < 9; ++tap) {
            const int ky = tap / 3, kx = tap - ky * 3;
            half8 Bf[4];
#pragma unroll
            for (int nt = 0; nt < 4; ++nt) Bf[nt] = wrep[(tap * 4 + nt) * 64 + lane];
#pragma unroll
            for (int mt = 0; mt < 4; ++mt) {
                int r = w * 4 + gr * 2 + (mt >> 1);       // wave row 0..3
                int xh = mt & 1;
                half8 Af = *(const half8*)(tile + ((r + ky) * 34 + xh * 16 + ln15 + kx) * 32 + q * 8);
#pragma unroll
                for (int nt = 0; nt < 4; ++nt)
                    acc[mt][nt] = __builtin_amdgcn_mfma_f32_16x16x32_f16(Af, Bf[nt], acc[mt][nt], 0, 0, 0);
            }
        }
#pragma unroll
        for (int mt = 0; mt < 4; ++mt)
#pragma unroll
            for (int nt = 0; nt < 4; ++nt)
#pragma unroll
                for (int rg = 0; rg < 4; ++rg)
                    partial[nt] += fmaxf(acc[mt][nt][rg], 0.f);
    }

    // reduce pixel sums across quad groups (same oc on lane&15)
#pragma unroll
    for (int nt = 0; nt < 4; ++nt) {
        float v = partial[nt];
        v += __shfl_xor(v, 16);
        v += __shfl_xor(v, 32);
        if (lane < 16) atomicAdd(&lsum[nt * 16 + ln15], v);
    }
    __syncthreads();
    const int cell = (yt >> 2) * 4 + (xt >> 1);
    if (t < 64) atomicAdd(&sacc[(((b << 6) + t) << 4) + cell], lsum[t]);
}

// ===========================================================================
// phase feature finalize
// ===========================================================================
__global__ void __launch_bounds__(64) finalize_phase(const float* __restrict__ psum,
                                                     const float* __restrict__ psumsq,
                                                     const unsigned* __restrict__ phist,
                                                     float* __restrict__ comb,
                                                     float* __restrict__ dout) {
    int t = threadIdx.x;
    if (t < 16) {
        const float N = 262144.f;
        float s = psum[t];
        float mean = s / N;
        float var = (psumsq[t] - s * s / N) / (N - 1.f);
        float sd = sqrtf(fmaxf(var, 0.f));
        float ent = 0.f;
        for (int i = 0; i < 64; ++i) {
            float p = (float)phist[t * 64 + i] / N;
            ent -= p * logf(p + 1e-10f);
        }
        dout[17408 + t * 3 + 0] = mean;
        dout[17408 + t * 3 + 1] = sd;
        dout[17408 + t * 3 + 2] = ent;
        float* cb = comb + t * 1091 + 1088;
        cb[0] = mean; cb[1] = sd; cb[2] = ent;
    }
}

// ===========================================================================
__global__ void __launch_bounds__(256) finalize_spatial(const float* __restrict__ sacc,
                                                        float* __restrict__ comb,
                                                        float* __restrict__ dout) {
    int idx = blockIdx.x * 256 + threadIdx.x;     // 16384
    int b = idx >> 10, j = idx & 1023;
    float v = sacc[idx] * (1.0f / 4096.0f);
    dout[1024 + idx] = v;
    comb[b * 1091 + 64 + j] = v;
}

// ===========================================================================
__global__ void __launch_bounds__(256) fc1_kernel(const float* __restrict__ comb,
                                                  const float* __restrict__ W1,
                                                  const float* __restrict__ B1,
                                                  float* __restrict__ out1) {
    __shared__ float c[1091];
    const int blk = blockIdx.x;                   // 32 blocks
    const int bb = blk >> 1;
    const int o = ((blk & 1) << 8) + threadIdx.x;
    for (int i = threadIdx.x; i < 1091; i += 256) c[i] = comb[bb * 1091 + i];
    __syncthreads();
    const float* w = W1 + (long long)o * 1091;
    float acc = B1[o];
#pragma unroll 4
    for (int k = 0; k < 1091; ++k) acc += c[k] * w[k];
    out1[(bb << 9) + o] = fmaxf(acc, 0.f);
}

// ===========================================================================
__global__ void __launch_bounds__(128) fc2_ln(const float* __restrict__ out1,
                                              const float* __restrict__ W2,
                                              const float* __restrict__ B2,
                                              const float* __restrict__ g,
                                              const float* __restrict__ beta,
                                              float* __restrict__ dout) {
    __shared__ float c[512];
    __shared__ float red[4];
    const int b = blockIdx.x, t = threadIdx.x;
    for (int i = t; i < 512; i += 128) c[i] = out1[b * 512 + i];
    __syncthreads();
    const float* w = W2 + t * 512;
    float acc = B2[t];
#pragma unroll 4
    for (int k = 0; k < 512; ++k) acc += c[k] * w[k];
    float s = acc;
    for (int off = 32; off > 0; off >>= 1) s += __shfl_down(s, off);
    if ((t & 63) == 0) red[t >> 6] = s;
    __syncthreads();
    float mu = (red[0] + red[1]) * (1.0f / 128.0f);
    float d = acc - mu;
    float q = d * d;
    for (int off = 32; off > 0; off >>= 1) q += __shfl_down(q, off);
    if ((t & 63) == 0) red[2 + (t >> 6)] = q;
    __syncthreads();
    float var = (red[2] + red[3]) * (1.0f / 128.0f);
    dout[17456 + b * 128 + t] = d / sqrtf(var + 1e-5f) * g[t] + beta[t];
}

// ===========================================================================
// launcher
// ===========================================================================
extern "C" void kernel_launch(void* const* d_in, const int* in_sizes, int n_in,
                              void* d_out, int out_size, void* d_ws, size_t ws_size,
                              hipStream_t stream) {
    const float* img = (const float*)d_in[0];
    const float* rec = (const float*)d_in[1];
    const float* w1  = (const float*)d_in[2];
    const float* c1b = (const float*)d_in[3];
    const float* w2  = (const float*)d_in[4];
    const float* c2b = (const float*)d_in[5];
    const float* fw1 = (const float*)d_in[6];
    const float* fb1 = (const float*)d_in[7];
    const float* fw2 = (const float*)d_in[8];
    const float* fb2 = (const float*)d_in[9];
    const float* lng = (const float*)d_in[10];
    const float* lnb = (const float*)d_in[11];
    float* out = (float*)d_out;

    float* ws = (float*)d_ws;
    float2* rowfft = (float2*)ws;                 // region0 (later grad)
    float* grad    = ws;                          // alias (rowfft dead after fft_cols)
    float* magT    = ws + OFF_BIG;                // region1
    _Float16* h1   = (_Float16*)(ws + OFF_BIG);   // alias (magT dead after topk) NHWC
    float* small_  = ws + OFF_SMALL;
    float* sacc    = small_;                      // 16384
    float* psum    = small_ + 16384;              // 16
    float* psumsq  = small_ + 16400;              // 16
    unsigned* phist = (unsigned*)(small_ + 16416);// 1024
    unsigned* mhist = (unsigned*)(small_ + 17440);// 65536
    float* dom     = small_ + 82976;              // 2048
    float* comb    = small_ + 85024;              // 17456
    float* out1    = small_ + 102480;             // 8192
    _Float16* wrep = (_Float16*)(small_ + 110672);// 18432 f16 = 9216 dwords

    zero_kernel<<<325, 256, 0, stream>>>(sacc, 82976);
    wrepack_kernel<<<72, 256, 0, stream>>>(w2, wrep);
    fft_rows<<<8192, 256, 0, stream>>>(img, rowfft);
    fft_cols<<<1024, 256, 0, stream>>>(rowfft, magT, psum, psumsq, phist);
    mag_hist<<<256, 256, 0, stream>>>(magT, mhist);
    topk_sort<<<16, 256, 0, stream>>>(magT, mhist, dom);
    sims_kernel<<<1, 256, 0, stream>>>(dom, rec, comb, out);
    grad_kernel<<<16384, 256, 0, stream>>>(img, grad);
    conv1_pool<<<4096, 256, 0, stream>>>(grad, w1, c1b, h1);
    conv2_mfma<<<2048, 256, 0, stream>>>(h1, (const half8*)wrep, c2b, sacc);
    finalize_phase<<<1, 64, 0, stream>>>(psum, psumsq, phist, comb, out);
    finalize_spatial<<<64, 256, 0, stream>>>(sacc, comb, out);
    fc1_kernel<<<32, 256, 0, stream>>>(comb, fw1, fb1, out1);
    fc2_ln<<<16, 128, 0, stream>>>(out1, fw2, fb2, lng, lnb, out);
}

// Round 3
// 549.429 us; speedup vs baseline: 3.4731x; 1.9291x over previous
//
#include <hip/hip_runtime.h>
#include <hip/hip_fp16.h>
#include <math.h>

// ---------------------------------------------------------------------------
// HolographicPatternExtractor  (B=16, C=1, H=W=512)
//  outputs (flat f32): sims[16,64] | spatial[16,1024] | phase_feats[16,3] | holo[16,128]
// ---------------------------------------------------------------------------

#define PI_F 3.14159274f          // float(np.pi)
#define TWO_PI_F 6.28318548f

typedef _Float16 half8 __attribute__((ext_vector_type(8)));
typedef float floatx4 __attribute__((ext_vector_type(4)));

// ---- workspace layout (dword offsets) ----
#define OFF_BIG   8388608
#define OFF_SMALL 25165824

// ===========================================================================
__global__ void __launch_bounds__(256) zero_kernel(float* p, int n) {
    int i = blockIdx.x * 256 + threadIdx.x;
    if (i < n) p[i] = 0.0f;
}

// ===========================================================================
// twiddle table: tw[half+p] = exp(-i*pi*p/half)
// ===========================================================================
__global__ void __launch_bounds__(256) twiddle_init(float2* __restrict__ tw) {
    int i = blockIdx.x * 256 + threadIdx.x;
    if (i < 512) {
        if (i == 0) { tw[0] = make_float2(1.f, 0.f); return; }
        int h = 31 - __clz(i);
        int H = 1 << h;
        float sn, cs;
        sincosf(-PI_F * (float)(i - H) / (float)H, &sn, &cs);
        tw[i] = make_float2(cs, sn);
    }
}

// ===========================================================================
// FFT row pass (DIF, natural input order, bit-reversed output order — OK:
// all consumers are order-invariant). One 512-pt FFT per block.
// ===========================================================================
__global__ void __launch_bounds__(256) fft_rows(const float* __restrict__ img,
                                                const float2* __restrict__ twg,
                                                float2* __restrict__ rowfft) {
    __shared__ float2 s[512];
    __shared__ float2 tw[512];
    const int t = threadIdx.x;
    const int row = blockIdx.x;                 // b*512 + y
    const float* x = img + (long long)row * 512;

    for (int i = t; i < 512; i += 256) tw[i] = twg[i];
    for (int i = t; i < 512; i += 256) s[i] = make_float2(x[i], 0.f);
    __syncthreads();
#pragma unroll
    for (int st = 9; st >= 1; --st) {
        const int half = 1 << (st - 1);
        const int pos = t & (half - 1);
        const int grp = t >> (st - 1);
        const int i1 = (grp << st) + pos;
        const int i2 = i1 + half;
        float2 w = tw[half + pos];
        float2 a = s[i1], b = s[i2];
        float dx = a.x - b.x, dy = a.y - b.y;
        s[i1] = make_float2(a.x + b.x, a.y + b.y);
        s[i2] = make_float2(dx * w.x - dy * w.y, dx * w.y + dy * w.x);
        __syncthreads();
    }
    for (int i = t; i < 512; i += 256) rowfft[(long long)row * 512 + i] = s[i];
}

// ===========================================================================
// FFT column pass (DIF): 8 columns per block; fuse magnitude (transposed
// store) + phase statistics (sum, sumsq, 64-bin histogram)
// ===========================================================================
__global__ void __launch_bounds__(256) fft_cols(const float2* __restrict__ rowfft,
                                                const float2* __restrict__ twg,
                                                float* __restrict__ magT,
                                                float* __restrict__ psum,
                                                float* __restrict__ psumsq,
                                                unsigned* __restrict__ phist) {
    __shared__ float2 s[8 * 512];               // column c contiguous at c*512
    __shared__ float2 tw[512];
    __shared__ unsigned ph[64];
    __shared__ float red[8];
    const int t = threadIdx.x;
    const int b = blockIdx.x >> 6;
    const int x0 = (blockIdx.x & 63) * 8;

    for (int i = t; i < 512; i += 256) tw[i] = twg[i];
    if (t < 64) ph[t] = 0u;
    for (int idx = t; idx < 8 * 512; idx += 256) {
        int y = idx >> 3;
        int c = idx & 7;
        s[c * 512 + y] = rowfft[((long long)(b * 512 + y)) * 512 + x0 + c];
    }
    __syncthreads();

    const int c = t >> 5;                       // 8 columns x 32 threads
    const int j0 = t & 31;
    float2* sc = s + c * 512;
#pragma unroll
    for (int st = 9; st >= 1; --st) {
        const int half = 1 << (st - 1);
#pragma unroll
        for (int k = 0; k < 8; ++k) {
            int j = j0 + (k << 5);
            int pos = j & (half - 1);
            int grp = j >> (st - 1);
            int i1 = (grp << st) + pos;
            int i2 = i1 + half;
            float2 w = tw[half + pos];
            float2 a = sc[i1], bb = sc[i2];
            float dx = a.x - bb.x, dy = a.y - bb.y;
            sc[i1] = make_float2(a.x + bb.x, a.y + bb.y);
            sc[i2] = make_float2(dx * w.x - dy * w.y, dx * w.y + dy * w.x);
        }
        __syncthreads();
    }

    float lsum = 0.f, lsq = 0.f;
    for (int idx = t; idx < 8 * 512; idx += 256) {
        int cc = idx >> 9;
        int y = idx & 511;
        float2 v = s[cc * 512 + y];
        float mag = sqrtf(v.x * v.x + v.y * v.y);
        magT[((long long)(b * 512 + x0 + cc)) * 512 + y] = mag;
        float phv = atan2f(v.y, v.x);
        lsum += phv;
        lsq += phv * phv;
        int bin = (int)floorf((phv + PI_F) / TWO_PI_F * 64.0f);
        bin = min(max(bin, 0), 63);
        atomicAdd(&ph[bin], 1u);
    }
    for (int off = 32; off > 0; off >>= 1) {
        lsum += __shfl_down(lsum, off);
        lsq  += __shfl_down(lsq, off);
    }
    if ((t & 63) == 0) { red[t >> 6] = lsum; red[4 + (t >> 6)] = lsq; }
    __syncthreads();
    if (t == 0) {
        atomicAdd(psum + b,   red[0] + red[1] + red[2] + red[3]);
        atomicAdd(psumsq + b, red[4] + red[5] + red[6] + red[7]);
    }
    if (t < 64 && ph[t]) atomicAdd(&phist[b * 64 + t], ph[t]);
}

// ===========================================================================
// magnitude histogram for top-k threshold (bits>>19 monotone for mag>=0)
// ===========================================================================
__global__ void __launch_bounds__(256) mag_hist(const float* __restrict__ magT,
                                                unsigned* __restrict__ mhist) {
    __shared__ unsigned h[4096];
    for (int i = threadIdx.x; i < 4096; i += 256) h[i] = 0u;
    __syncthreads();
    int b = blockIdx.x >> 4;
    int chunk = blockIdx.x & 15;
    const float* m = magT + (long long)b * 262144 + chunk * 16384;
    for (int i = threadIdx.x; i < 16384; i += 256) {
        unsigned bits = __float_as_uint(m[i]);
        unsigned bin = min(bits >> 19, 4095u);
        atomicAdd(&h[bin], 1u);
    }
    __syncthreads();
    for (int i = threadIdx.x; i < 4096; i += 256)
        if (h[i]) atomicAdd(&mhist[b * 4096 + i], h[i]);
}

// ===========================================================================
// top-k: threshold bin from histogram suffix-count
// ===========================================================================
__global__ void __launch_bounds__(256) thresh_kernel(const unsigned* __restrict__ mhist,
                                                     int* __restrict__ selbin) {
    __shared__ unsigned csum[256];
    const int b = blockIdx.x, t = threadIdx.x;
    unsigned s = 0;
    for (int i = 0; i < 16; ++i) s += mhist[b * 4096 + t * 16 + i];
    csum[t] = s;
    __syncthreads();
    if (t == 0) {
        unsigned acc = 0; int chunk = 0;
        for (int i = 255; i >= 0; --i) {
            acc += csum[i];
            if (acc >= 128u) { chunk = i; break; }
        }
        unsigned acc2 = acc - csum[chunk];      // count strictly above chunk
        int tb = chunk * 16;
        for (int i = chunk * 16 + 15; i >= chunk * 16; --i) {
            acc2 += mhist[b * 4096 + i];
            if (acc2 >= 128u) { tb = i; break; }
        }
        selbin[b] = tb;
    }
}

// ===========================================================================
// top-k: parallel candidate collection (256 blocks)
// ===========================================================================
#define TK_CAP 4096
__global__ void __launch_bounds__(256) collect_kernel(const float* __restrict__ magT,
                                                      const int* __restrict__ selbin,
                                                      float* __restrict__ cand,
                                                      unsigned* __restrict__ ccnt) {
    const int blk = blockIdx.x;
    const int b = blk >> 4, chunk = blk & 15;
    const unsigned tb = (unsigned)selbin[b];
    const floatx4* m = (const floatx4*)(magT + (long long)b * 262144 + chunk * 16384);
    float* cb = cand + b * TK_CAP;
    for (int i = threadIdx.x; i < 4096; i += 256) {
        floatx4 v = m[i];
#pragma unroll
        for (int k = 0; k < 4; ++k) {
            float x = v[k];
            unsigned bin = min(__float_as_uint(x) >> 19, 4095u);
            if (bin >= tb) {
                unsigned p = atomicAdd(&ccnt[b], 1u);
                if (p < TK_CAP) cb[p] = x;
            }
        }
    }
}

// ===========================================================================
// top-k: bitonic sort descending of candidates -> dom[b][128]
// ===========================================================================
__global__ void __launch_bounds__(1024) sort_kernel(const float* __restrict__ cand,
                                                    const unsigned* __restrict__ ccnt,
                                                    float* __restrict__ dom) {
    __shared__ float c[TK_CAP];
    const int b = blockIdx.x, t = threadIdx.x;
    const unsigned n = min(ccnt[b], (unsigned)TK_CAP);
    int P = 256;
    while (P < (int)n) P <<= 1;                 // 256..4096
    for (int i = t; i < P; i += 1024) c[i] = (i < (int)n) ? cand[b * TK_CAP + i] : -1.0f;
    __syncthreads();
    for (int k = 2; k <= P; k <<= 1) {
        for (int j = k >> 1; j > 0; j >>= 1) {
            for (int i = t; i < P; i += 1024) {
                int ixj = i ^ j;
                if (ixj > i) {
                    float a = c[i], d = c[ixj];
                    bool up = ((i & k) == 0);
                    if (up ? (a < d) : (a > d)) { c[i] = d; c[ixj] = a; }
                }
            }
            __syncthreads();
        }
    }
    if (t < 128) dom[b * 128 + t] = c[t];
}

// ===========================================================================
// sims = normalize(dom) @ normalize(receptors)^T
// ===========================================================================
__global__ void __launch_bounds__(256) sims_kernel(const float* __restrict__ dom,
                                                   const float* __restrict__ rec,
                                                   float* __restrict__ comb,
                                                   float* __restrict__ dout) {
    __shared__ float sd[16 * 128];
    __shared__ float sr[64 * 128];
    __shared__ float scale[80];
    const int t = threadIdx.x;
    for (int i = t; i < 2048; i += 256) sd[i] = dom[i];
    for (int i = t; i < 8192; i += 256) sr[i] = rec[i];
    __syncthreads();
    if (t < 80) {
        const float* base = (t < 16) ? (sd + t * 128) : (sr + (t - 16) * 128);
        float s = 0.f;
        for (int k = 0; k < 128; ++k) s += base[k] * base[k];
        scale[t] = 1.0f / fmaxf(sqrtf(s), 1e-12f);
    }
    __syncthreads();
    for (int o = t; o < 1024; o += 256) {
        int b = o >> 6, p = o & 63;
        const float* dv = sd + b * 128;
        const float* rv = sr + p * 128;
        float s = 0.f;
        for (int k = 0; k < 128; ++k) s += dv[k] * rv[k];
        float val = s * scale[b] * scale[16 + p];
        dout[b * 64 + p] = val;
        comb[b * 1091 + p] = val;
    }
}

// ===========================================================================
// gradients: gmag / gori
// ===========================================================================
__global__ void __launch_bounds__(256) grad_kernel(const float* __restrict__ img,
                                                   float* __restrict__ grad) {
    int idx = blockIdx.x * 256 + threadIdx.x;     // 16*262144
    int b = idx >> 18;
    int r = idx & 262143;
    int y = r >> 9, x = r & 511;
    const float* im = img + (long long)b * 262144;
    int yp = min(y + 1, 511), ym = max(y - 1, 0);
    int xp = min(x + 1, 511), xm = max(x - 1, 0);
    float fy = (y == 0 || y == 511) ? 1.f : 0.5f;
    float fx = (x == 0 || x == 511) ? 1.f : 0.5f;
    float gy = (im[yp * 512 + x] - im[ym * 512 + x]) * fy;
    float gx = (im[y * 512 + xp] - im[y * 512 + xm]) * fx;
    grad[((long long)(b * 2)) * 262144 + r]     = sqrtf(gx * gx + gy * gy);
    grad[((long long)(b * 2 + 1)) * 262144 + r] = atan2f(gy, gx);
}

// ===========================================================================
// conv1 (2->32, 3x3 SAME) + ReLU + maxpool2 -> h1 NHWC fp16 [b][y][x][ic=32]
// ===========================================================================
__global__ void __launch_bounds__(256) conv1_pool(const float* __restrict__ grad,
                                                  const float* __restrict__ w1,
                                                  const float* __restrict__ c1b,
                                                  _Float16* __restrict__ h1) {
    int idx = blockIdx.x * 256 + threadIdx.x;     // 16*65536
    int b = idx >> 16;
    int r = idx & 65535;
    int py = r >> 8, px = r & 255;
    int y0 = 2 * py - 1, x0 = 2 * px - 1;
    float in[2][4][4];
#pragma unroll
    for (int ic = 0; ic < 2; ++ic) {
        const float* g = grad + ((long long)(b * 2 + ic)) * 262144;
#pragma unroll
        for (int dy = 0; dy < 4; ++dy) {
            int gy = y0 + dy;
            bool oky = (unsigned)gy < 512u;
#pragma unroll
            for (int dx = 0; dx < 4; ++dx) {
                int gx = x0 + dx;
                in[ic][dy][dx] = (oky && (unsigned)gx < 512u) ? g[gy * 512 + gx] : 0.f;
            }
        }
    }
    union { _Float16 h[32]; floatx4 v[4]; } outp;
#pragma unroll 4
    for (int oc = 0; oc < 32; ++oc) {
        float wv[18];
#pragma unroll
        for (int i = 0; i < 18; ++i) wv[i] = w1[oc * 18 + i];
        float bias = c1b[oc];
        float mx = -3.4e38f;
#pragma unroll
        for (int yy = 0; yy < 2; ++yy)
#pragma unroll
            for (int xx = 0; xx < 2; ++xx) {
                float acc = bias;
#pragma unroll
                for (int ic = 0; ic < 2; ++ic)
#pragma unroll
                    for (int ky = 0; ky < 3; ++ky)
#pragma unroll
                        for (int kx = 0; kx < 3; ++kx)
                            acc += wv[(ic * 3 + ky) * 3 + kx] * in[ic][yy + ky][xx + kx];
                mx = fmaxf(mx, acc);
            }
        outp.h[oc] = (_Float16)fmaxf(mx, 0.f);
    }
    floatx4* dst = (floatx4*)(h1 + ((size_t)idx) * 32);
#pragma unroll
    for (int c = 0; c < 4; ++c) dst[c] = outp.v[c];
}

// ===========================================================================
// weight repack for conv2 MFMA: wrep[tap][nt][lane][j] = w2[oc][ic][tap]
// ===========================================================================
__global__ void __launch_bounds__(256) wrepack_kernel(const float* __restrict__ w2,
                                                      _Float16* __restrict__ wrep) {
    int idx = blockIdx.x * 256 + threadIdx.x;   // 18432
    if (idx < 18432) {
        int j = idx & 7;
        int lane = (idx >> 3) & 63;
        int nt = (idx >> 9) & 3;
        int tap = idx >> 11;
        int oc = nt * 16 + (lane & 15);
        int ic = (lane >> 4) * 8 + j;
        wrep[idx] = (_Float16)w2[(oc * 32 + ic) * 9 + tap];
    }
}

// ===========================================================================
// conv2 (32->64, 3x3 SAME) + ReLU + 64x64 avg-pool partials — implicit GEMM
// via mfma_f32_16x16x32_f16.
// ===========================================================================
__global__ void __launch_bounds__(256) conv2_mfma(const _Float16* __restrict__ h1,
                                                  const half8* __restrict__ wrep,
                                                  const float* __restrict__ c2b,
                                                  float* __restrict__ sacc) {
    __shared__ _Float16 tile[18 * 34 * 32];     // [row][px][ic] 39,168 B
    __shared__ float lsum[64];
    const int blk = blockIdx.x;                 // b*128 + yt*8 + xt
    const int b  = blk >> 7;
    const int yt = (blk >> 3) & 15;
    const int xt = blk & 7;
    const int y0 = yt * 16, x0 = xt * 32;
    const int t = threadIdx.x;
    if (t < 64) lsum[t] = 0.f;

    for (int c = t; c < 18 * 136; c += 256) {
        int row = c / 136;
        int chunk = c - row * 136;
        int gy = y0 - 1 + row;
        int px = chunk >> 2;
        int gx = x0 - 1 + px;
        floatx4 v = {0.f, 0.f, 0.f, 0.f};
        if ((unsigned)gy < 256u && (unsigned)gx < 256u)
            v = *(const floatx4*)(h1 + (((size_t)(b * 256 + gy)) * 256 + gx) * 32 + (chunk & 3) * 8);
        *(floatx4*)(tile + (row * 34 + px) * 32 + (chunk & 3) * 8) = v;
    }
    __syncthreads();

    const int w = t >> 6, lane = t & 63;
    const int q = lane >> 4, ln15 = lane & 15;
    float bias[4];
#pragma unroll
    for (int nt = 0; nt < 4; ++nt) bias[nt] = c2b[nt * 16 + ln15];
    float partial[4] = {0.f, 0.f, 0.f, 0.f};

#pragma unroll 1
    for (int gr = 0; gr < 2; ++gr) {
        floatx4 acc[4][4];
#pragma unroll
        for (int mt = 0; mt < 4; ++mt)
#pragma unroll
            for (int nt = 0; nt < 4; ++nt)
                acc[mt][nt] = floatx4{bias[nt], bias[nt], bias[nt], bias[nt]};
#pragma unroll 1
        for (int tap = 0; tap < 9; ++tap) {
            const int ky = tap / 3, kx = tap - ky * 3;
            half8 Bf[4];
#pragma unroll
            for (int nt = 0; nt < 4; ++nt) Bf[nt] = wrep[(tap * 4 + nt) * 64 + lane];
#pragma unroll
            for (int mt = 0; mt < 4; ++mt) {
                int r = w * 4 + gr * 2 + (mt >> 1);
                int xh = mt & 1;
                half8 Af = *(const half8*)(tile + ((r + ky) * 34 + xh * 16 + ln15 + kx) * 32 + q * 8);
#pragma unroll
                for (int nt = 0; nt < 4; ++nt)
                    acc[mt][nt] = __builtin_amdgcn_mfma_f32_16x16x32_f16(Af, Bf[nt], acc[mt][nt], 0, 0, 0);
            }
        }
#pragma unroll
        for (int mt = 0; mt < 4; ++mt)
#pragma unroll
            for (int nt = 0; nt < 4; ++nt)
#pragma unroll
                for (int rg = 0; rg < 4; ++rg)
                    partial[nt] += fmaxf(acc[mt][nt][rg], 0.f);
    }

#pragma unroll
    for (int nt = 0; nt < 4; ++nt) {
        float v = partial[nt];
        v += __shfl_xor(v, 16);
        v += __shfl_xor(v, 32);
        if (lane < 16) atomicAdd(&lsum[nt * 16 + ln15], v);
    }
    __syncthreads();
    const int cell = (yt >> 2) * 4 + (xt >> 1);
    if (t < 64) atomicAdd(&sacc[(((b << 6) + t) << 4) + cell], lsum[t]);
}

// ===========================================================================
__global__ void __launch_bounds__(64) finalize_phase(const float* __restrict__ psum,
                                                     const float* __restrict__ psumsq,
                                                     const unsigned* __restrict__ phist,
                                                     float* __restrict__ comb,
                                                     float* __restrict__ dout) {
    int t = threadIdx.x;
    if (t < 16) {
        const float N = 262144.f;
        float s = psum[t];
        float mean = s / N;
        float var = (psumsq[t] - s * s / N) / (N - 1.f);
        float sd = sqrtf(fmaxf(var, 0.f));
        float ent = 0.f;
        for (int i = 0; i < 64; ++i) {
            float p = (float)phist[t * 64 + i] / N;
            ent -= p * logf(p + 1e-10f);
        }
        dout[17408 + t * 3 + 0] = mean;
        dout[17408 + t * 3 + 1] = sd;
        dout[17408 + t * 3 + 2] = ent;
        float* cb = comb + t * 1091 + 1088;
        cb[0] = mean; cb[1] = sd; cb[2] = ent;
    }
}

// ===========================================================================
__global__ void __launch_bounds__(256) finalize_spatial(const float* __restrict__ sacc,
                                                        float* __restrict__ comb,
                                                        float* __restrict__ dout) {
    int idx = blockIdx.x * 256 + threadIdx.x;     // 16384
    int b = idx >> 10, j = idx & 1023;
    float v = sacc[idx] * (1.0f / 4096.0f);
    dout[1024 + idx] = v;
    comb[b * 1091 + 64 + j] = v;
}

// ===========================================================================
__global__ void __launch_bounds__(256) fc1_kernel(const float* __restrict__ comb,
                                                  const float* __restrict__ W1,
                                                  const float* __restrict__ B1,
                                                  float* __restrict__ out1) {
    __shared__ float c[1091];
    const int blk = blockIdx.x;                   // 32 blocks
    const int bb = blk >> 1;
    const int o = ((blk & 1) << 8) + threadIdx.x;
    for (int i = threadIdx.x; i < 1091; i += 256) c[i] = comb[bb * 1091 + i];
    __syncthreads();
    const float* w = W1 + (long long)o * 1091;
    float acc = B1[o];
#pragma unroll 4
    for (int k = 0; k < 1091; ++k) acc += c[k] * w[k];
    out1[(bb << 9) + o] = fmaxf(acc, 0.f);
}

// ===========================================================================
__global__ void __launch_bounds__(128) fc2_ln(const float* __restrict__ out1,
                                              const float* __restrict__ W2,
                                              const float* __restrict__ B2,
                                              const float* __restrict__ g,
                                              const float* __restrict__ beta,
                                              float* __restrict__ dout) {
    __shared__ float c[512];
    __shared__ float red[4];
    const int b = blockIdx.x, t = threadIdx.x;
    for (int i = t; i < 512; i += 128) c[i] = out1[b * 512 + i];
    __syncthreads();
    const float* w = W2 + t * 512;
    float acc = B2[t];
#pragma unroll 4
    for (int k = 0; k < 512; ++k) acc += c[k] * w[k];
    float s = acc;
    for (int off = 32; off > 0; off >>= 1) s += __shfl_down(s, off);
    if ((t & 63) == 0) red[t >> 6] = s;
    __syncthreads();
    float mu = (red[0] + red[1]) * (1.0f / 128.0f);
    float d = acc - mu;
    float q = d * d;
    for (int off = 32; off > 0; off >>= 1) q += __shfl_down(q, off);
    if ((t & 63) == 0) red[2 + (t >> 6)] = q;
    __syncthreads();
    float var = (red[2] + red[3]) * (1.0f / 128.0f);
    dout[17456 + b * 128 + t] = d / sqrtf(var + 1e-5f) * g[t] + beta[t];
}

// ===========================================================================
// launcher
// ===========================================================================
extern "C" void kernel_launch(void* const* d_in, const int* in_sizes, int n_in,
                              void* d_out, int out_size, void* d_ws, size_t ws_size,
                              hipStream_t stream) {
    const float* img = (const float*)d_in[0];
    const float* rec = (const float*)d_in[1];
    const float* w1  = (const float*)d_in[2];
    const float* c1b = (const float*)d_in[3];
    const float* w2  = (const float*)d_in[4];
    const float* c2b = (const float*)d_in[5];
    const float* fw1 = (const float*)d_in[6];
    const float* fb1 = (const float*)d_in[7];
    const float* fw2 = (const float*)d_in[8];
    const float* fb2 = (const float*)d_in[9];
    const float* lng = (const float*)d_in[10];
    const float* lnb = (const float*)d_in[11];
    float* out = (float*)d_out;

    float* ws = (float*)d_ws;
    float2* rowfft = (float2*)ws;                 // region0 (later grad)
    float* grad    = ws;                          // alias (rowfft dead after fft_cols)
    float* magT    = ws + OFF_BIG;                // region1
    _Float16* h1   = (_Float16*)(ws + OFF_BIG);   // alias (magT dead after collect) NHWC
    float* small_  = ws + OFF_SMALL;
    float* sacc    = small_;                      // 16384
    float* psum    = small_ + 16384;              // 16
    float* psumsq  = small_ + 16400;              // 16
    unsigned* phist = (unsigned*)(small_ + 16416);// 1024
    unsigned* mhist = (unsigned*)(small_ + 17440);// 65536
    unsigned* ccnt  = (unsigned*)(small_ + 82976);// 16    (zeroed range ends at 82992)
    int* selbin    = (int*)(small_ + 82992);      // 16
    float* dom     = small_ + 83008;              // 2048
    float* comb    = small_ + 85056;              // 17456
    float* out1    = small_ + 102512;             // 8192
    _Float16* wrep = (_Float16*)(small_ + 110704);// 18432 f16 = 9216 dwords
    float2* twg    = (float2*)(small_ + 119920);  // 512 float2 = 1024 dwords
    float* cand    = small_ + 120944;             // 16*4096 = 65536 dwords

    zero_kernel<<<325, 256, 0, stream>>>(sacc, 82992);
    twiddle_init<<<2, 256, 0, stream>>>(twg);
    wrepack_kernel<<<72, 256, 0, stream>>>(w2, wrep);
    fft_rows<<<8192, 256, 0, stream>>>(img, twg, rowfft);
    fft_cols<<<1024, 256, 0, stream>>>(rowfft, twg, magT, psum, psumsq, phist);
    mag_hist<<<256, 256, 0, stream>>>(magT, mhist);
    thresh_kernel<<<16, 256, 0, stream>>>(mhist, selbin);
    collect_kernel<<<256, 256, 0, stream>>>(magT, selbin, cand, ccnt);
    sort_kernel<<<16, 1024, 0, stream>>>(cand, ccnt, dom);
    sims_kernel<<<1, 256, 0, stream>>>(dom, rec, comb, out);
    grad_kernel<<<16384, 256, 0, stream>>>(img, grad);
    conv1_pool<<<4096, 256, 0, stream>>>(grad, w1, c1b, h1);
    conv2_mfma<<<2048, 256, 0, stream>>>(h1, (const half8*)wrep, c2b, sacc);
    finalize_phase<<<1, 64, 0, stream>>>(psum, psumsq, phist, comb, out);
    finalize_spatial<<<64, 256, 0, stream>>>(sacc, comb, out);
    fc1_kernel<<<32, 256, 0, stream>>>(comb, fw1, fb1, out1);
    fc2_ln<<<16, 128, 0, stream>>>(out1, fw2, fb2, lng, lnb, out);
}

// Round 4
// 377.964 us; speedup vs baseline: 5.0486x; 1.4537x over previous
//
#include <hip/hip_runtime.h>
#include <hip/hip_fp16.h>
#include <math.h>

// ---------------------------------------------------------------------------
// HolographicPatternExtractor  (B=16, C=1, H=W=512)
//  outputs (flat f32): sims[16,64] | spatial[16,1024] | phase_feats[16,3] | holo[16,128]
// ---------------------------------------------------------------------------

#define PI_F 3.14159274f          // float(np.pi)
#define TWO_PI_F 6.28318548f

typedef _Float16 half8 __attribute__((ext_vector_type(8)));
typedef float floatx4 __attribute__((ext_vector_type(4)));

// ---- workspace layout (dword offsets) ----
#define OFF_BIG   8388608
#define OFF_SMALL 25165824

// ===========================================================================
__global__ void __launch_bounds__(256) zero_kernel(float* p, int n) {
    int i = blockIdx.x * 256 + threadIdx.x;
    if (i < n) p[i] = 0.0f;
}

// ===========================================================================
// twiddle table: tw[half+p] = exp(-i*pi*p/half)
// ===========================================================================
__global__ void __launch_bounds__(256) twiddle_init(float2* __restrict__ tw) {
    int i = blockIdx.x * 256 + threadIdx.x;
    if (i < 512) {
        if (i == 0) { tw[0] = make_float2(1.f, 0.f); return; }
        int h = 31 - __clz(i);
        int H = 1 << h;
        float sn, cs;
        sincosf(-PI_F * (float)(i - H) / (float)H, &sn, &cs);
        tw[i] = make_float2(cs, sn);
    }
}

// ===========================================================================
// FFT row pass (DIF, natural input order, bit-reversed output order — OK:
// all consumers are order-invariant). One 512-pt FFT per block.
// ===========================================================================
__global__ void __launch_bounds__(256) fft_rows(const float* __restrict__ img,
                                                const float2* __restrict__ twg,
                                                float2* __restrict__ rowfft) {
    __shared__ float2 s[512];
    __shared__ float2 tw[512];
    const int t = threadIdx.x;
    const int row = blockIdx.x;                 // b*512 + y
    const float* x = img + (long long)row * 512;

    for (int i = t; i < 512; i += 256) tw[i] = twg[i];
    for (int i = t; i < 512; i += 256) s[i] = make_float2(x[i], 0.f);
    __syncthreads();
#pragma unroll
    for (int st = 9; st >= 1; --st) {
        const int half = 1 << (st - 1);
        const int pos = t & (half - 1);
        const int grp = t >> (st - 1);
        const int i1 = (grp << st) + pos;
        const int i2 = i1 + half;
        float2 w = tw[half + pos];
        float2 a = s[i1], b = s[i2];
        float dx = a.x - b.x, dy = a.y - b.y;
        s[i1] = make_float2(a.x + b.x, a.y + b.y);
        s[i2] = make_float2(dx * w.x - dy * w.y, dx * w.y + dy * w.x);
        __syncthreads();
    }
    for (int i = t; i < 512; i += 256) rowfft[(long long)row * 512 + i] = s[i];
}

// ===========================================================================
// FFT column pass (DIF): 8 columns per block; fuse magnitude (transposed
// store) + phase statistics (sum, sumsq, 64-bin histogram)
// ===========================================================================
__global__ void __launch_bounds__(256) fft_cols(const float2* __restrict__ rowfft,
                                                const float2* __restrict__ twg,
                                                float* __restrict__ magT,
                                                float* __restrict__ psum,
                                                float* __restrict__ psumsq,
                                                unsigned* __restrict__ phist) {
    __shared__ float2 s[8 * 512];               // column c contiguous at c*512
    __shared__ float2 tw[512];
    __shared__ unsigned ph[64];
    __shared__ float red[8];
    const int t = threadIdx.x;
    const int b = blockIdx.x >> 6;
    const int x0 = (blockIdx.x & 63) * 8;

    for (int i = t; i < 512; i += 256) tw[i] = twg[i];
    if (t < 64) ph[t] = 0u;
    for (int idx = t; idx < 8 * 512; idx += 256) {
        int y = idx >> 3;
        int c = idx & 7;
        s[c * 512 + y] = rowfft[((long long)(b * 512 + y)) * 512 + x0 + c];
    }
    __syncthreads();

    const int c = t >> 5;                       // 8 columns x 32 threads
    const int j0 = t & 31;
    float2* sc = s + c * 512;
#pragma unroll
    for (int st = 9; st >= 1; --st) {
        const int half = 1 << (st - 1);
#pragma unroll
        for (int k = 0; k < 8; ++k) {
            int j = j0 + (k << 5);
            int pos = j & (half - 1);
            int grp = j >> (st - 1);
            int i1 = (grp << st) + pos;
            int i2 = i1 + half;
            float2 w = tw[half + pos];
            float2 a = sc[i1], bb = sc[i2];
            float dx = a.x - bb.x, dy = a.y - bb.y;
            sc[i1] = make_float2(a.x + bb.x, a.y + bb.y);
            sc[i2] = make_float2(dx * w.x - dy * w.y, dx * w.y + dy * w.x);
        }
        __syncthreads();
    }

    float lsum = 0.f, lsq = 0.f;
    for (int idx = t; idx < 8 * 512; idx += 256) {
        int cc = idx >> 9;
        int y = idx & 511;
        float2 v = s[cc * 512 + y];
        float mag = sqrtf(v.x * v.x + v.y * v.y);
        magT[((long long)(b * 512 + x0 + cc)) * 512 + y] = mag;
        float phv = atan2f(v.y, v.x);
        lsum += phv;
        lsq += phv * phv;
        int bin = (int)floorf((phv + PI_F) / TWO_PI_F * 64.0f);
        bin = min(max(bin, 0), 63);
        atomicAdd(&ph[bin], 1u);
    }
    for (int off = 32; off > 0; off >>= 1) {
        lsum += __shfl_down(lsum, off);
        lsq  += __shfl_down(lsq, off);
    }
    if ((t & 63) == 0) { red[t >> 6] = lsum; red[4 + (t >> 6)] = lsq; }
    __syncthreads();
    if (t == 0) {
        atomicAdd(psum + b,   red[0] + red[1] + red[2] + red[3]);
        atomicAdd(psumsq + b, red[4] + red[5] + red[6] + red[7]);
    }
    if (t < 64 && ph[t]) atomicAdd(&phist[b * 64 + t], ph[t]);
}

// ===========================================================================
// magnitude histogram for top-k threshold (bits>>19 monotone for mag>=0)
// ===========================================================================
__global__ void __launch_bounds__(256) mag_hist(const float* __restrict__ magT,
                                                unsigned* __restrict__ mhist) {
    __shared__ unsigned h[4096];
    for (int i = threadIdx.x; i < 4096; i += 256) h[i] = 0u;
    __syncthreads();
    int b = blockIdx.x >> 4;
    int chunk = blockIdx.x & 15;
    const float* m = magT + (long long)b * 262144 + chunk * 16384;
    for (int i = threadIdx.x; i < 16384; i += 256) {
        unsigned bits = __float_as_uint(m[i]);
        unsigned bin = min(bits >> 19, 4095u);
        atomicAdd(&h[bin], 1u);
    }
    __syncthreads();
    for (int i = threadIdx.x; i < 4096; i += 256)
        if (h[i]) atomicAdd(&mhist[b * 4096 + i], h[i]);
}

// ===========================================================================
// top-k: threshold bin from histogram suffix-count
// ===========================================================================
__global__ void __launch_bounds__(256) thresh_kernel(const unsigned* __restrict__ mhist,
                                                     int* __restrict__ selbin) {
    __shared__ unsigned csum[256];
    const int b = blockIdx.x, t = threadIdx.x;
    unsigned s = 0;
    for (int i = 0; i < 16; ++i) s += mhist[b * 4096 + t * 16 + i];
    csum[t] = s;
    __syncthreads();
    if (t == 0) {
        unsigned acc = 0; int chunk = 0;
        for (int i = 255; i >= 0; --i) {
            acc += csum[i];
            if (acc >= 128u) { chunk = i; break; }
        }
        unsigned acc2 = acc - csum[chunk];      // count strictly above chunk
        int tb = chunk * 16;
        for (int i = chunk * 16 + 15; i >= chunk * 16; --i) {
            acc2 += mhist[b * 4096 + i];
            if (acc2 >= 128u) { tb = i; break; }
        }
        selbin[b] = tb;
    }
}

// ===========================================================================
// top-k: parallel candidate collection (256 blocks)
// ===========================================================================
#define TK_CAP 4096
__global__ void __launch_bounds__(256) collect_kernel(const float* __restrict__ magT,
                                                      const int* __restrict__ selbin,
                                                      float* __restrict__ cand,
                                                      unsigned* __restrict__ ccnt) {
    const int blk = blockIdx.x;
    const int b = blk >> 4, chunk = blk & 15;
    const unsigned tb = (unsigned)selbin[b];
    const floatx4* m = (const floatx4*)(magT + (long long)b * 262144 + chunk * 16384);
    float* cb = cand + b * TK_CAP;
    for (int i = threadIdx.x; i < 4096; i += 256) {
        floatx4 v = m[i];
#pragma unroll
        for (int k = 0; k < 4; ++k) {
            float x = v[k];
            unsigned bin = min(__float_as_uint(x) >> 19, 4095u);
            if (bin >= tb) {
                unsigned p = atomicAdd(&ccnt[b], 1u);
                if (p < TK_CAP) cb[p] = x;
            }
        }
    }
}

// ===========================================================================
// top-k: bitonic sort descending of candidates -> dom[b][128]
// ===========================================================================
__global__ void __launch_bounds__(1024) sort_kernel(const float* __restrict__ cand,
                                                    const unsigned* __restrict__ ccnt,
                                                    float* __restrict__ dom) {
    __shared__ float c[TK_CAP];
    const int b = blockIdx.x, t = threadIdx.x;
    const unsigned n = min(ccnt[b], (unsigned)TK_CAP);
    int P = 256;
    while (P < (int)n) P <<= 1;                 // 256..4096
    for (int i = t; i < P; i += 1024) c[i] = (i < (int)n) ? cand[b * TK_CAP + i] : -1.0f;
    __syncthreads();
    for (int k = 2; k <= P; k <<= 1) {
        for (int j = k >> 1; j > 0; j >>= 1) {
            for (int i = t; i < P; i += 1024) {
                int ixj = i ^ j;
                if (ixj > i) {
                    float a = c[i], d = c[ixj];
                    bool up = ((i & k) == 0);
                    if (up ? (a < d) : (a > d)) { c[i] = d; c[ixj] = a; }
                }
            }
            __syncthreads();
        }
    }
    if (t < 128) dom[b * 128 + t] = c[t];
}

// ===========================================================================
// sims = normalize(dom) @ normalize(receptors)^T
// ===========================================================================
__global__ void __launch_bounds__(256) sims_kernel(const float* __restrict__ dom,
                                                   const float* __restrict__ rec,
                                                   float* __restrict__ comb,
                                                   float* __restrict__ dout) {
    __shared__ float sd[16 * 128];
    __shared__ float sr[64 * 128];
    __shared__ float scale[80];
    const int t = threadIdx.x;
    for (int i = t; i < 2048; i += 256) sd[i] = dom[i];
    for (int i = t; i < 8192; i += 256) sr[i] = rec[i];
    __syncthreads();
    if (t < 80) {
        const float* base = (t < 16) ? (sd + t * 128) : (sr + (t - 16) * 128);
        float s = 0.f;
        for (int k = 0; k < 128; ++k) s += base[k] * base[k];
        scale[t] = 1.0f / fmaxf(sqrtf(s), 1e-12f);
    }
    __syncthreads();
    for (int o = t; o < 1024; o += 256) {
        int b = o >> 6, p = o & 63;
        const float* dv = sd + b * 128;
        const float* rv = sr + p * 128;
        float s = 0.f;
        for (int k = 0; k < 128; ++k) s += dv[k] * rv[k];
        float val = s * scale[b] * scale[16 + p];
        dout[b * 64 + p] = val;
        comb[b * 1091 + p] = val;
    }
}

// ===========================================================================
// gradients: gmag / gori
// ===========================================================================
__global__ void __launch_bounds__(256) grad_kernel(const float* __restrict__ img,
                                                   float* __restrict__ grad) {
    int idx = blockIdx.x * 256 + threadIdx.x;     // 16*262144
    int b = idx >> 18;
    int r = idx & 262143;
    int y = r >> 9, x = r & 511;
    const float* im = img + (long long)b * 262144;
    int yp = min(y + 1, 511), ym = max(y - 1, 0);
    int xp = min(x + 1, 511), xm = max(x - 1, 0);
    float fy = (y == 0 || y == 511) ? 1.f : 0.5f;
    float fx = (x == 0 || x == 511) ? 1.f : 0.5f;
    float gy = (im[yp * 512 + x] - im[ym * 512 + x]) * fy;
    float gx = (im[y * 512 + xp] - im[y * 512 + xm]) * fx;
    grad[((long long)(b * 2)) * 262144 + r]     = sqrtf(gx * gx + gy * gy);
    grad[((long long)(b * 2 + 1)) * 262144 + r] = atan2f(gy, gx);
}

// ===========================================================================
// conv1 (2->32, 3x3 SAME) + ReLU + maxpool2 -> h1 NHWC fp16 [b][y][x][ic=32]
// ===========================================================================
__global__ void __launch_bounds__(256) conv1_pool(const float* __restrict__ grad,
                                                  const float* __restrict__ w1,
                                                  const float* __restrict__ c1b,
                                                  _Float16* __restrict__ h1) {
    int idx = blockIdx.x * 256 + threadIdx.x;     // 16*65536
    int b = idx >> 16;
    int r = idx & 65535;
    int py = r >> 8, px = r & 255;
    int y0 = 2 * py - 1, x0 = 2 * px - 1;
    float in[2][4][4];
#pragma unroll
    for (int ic = 0; ic < 2; ++ic) {
        const float* g = grad + ((long long)(b * 2 + ic)) * 262144;
#pragma unroll
        for (int dy = 0; dy < 4; ++dy) {
            int gy = y0 + dy;
            bool oky = (unsigned)gy < 512u;
#pragma unroll
            for (int dx = 0; dx < 4; ++dx) {
                int gx = x0 + dx;
                in[ic][dy][dx] = (oky && (unsigned)gx < 512u) ? g[gy * 512 + gx] : 0.f;
            }
        }
    }
    union { _Float16 h[32]; floatx4 v[4]; } outp;
#pragma unroll 4
    for (int oc = 0; oc < 32; ++oc) {
        float wv[18];
#pragma unroll
        for (int i = 0; i < 18; ++i) wv[i] = w1[oc * 18 + i];
        float bias = c1b[oc];
        float mx = -3.4e38f;
#pragma unroll
        for (int yy = 0; yy < 2; ++yy)
#pragma unroll
            for (int xx = 0; xx < 2; ++xx) {
                float acc = bias;
#pragma unroll
                for (int ic = 0; ic < 2; ++ic)
#pragma unroll
                    for (int ky = 0; ky < 3; ++ky)
#pragma unroll
                        for (int kx = 0; kx < 3; ++kx)
                            acc += wv[(ic * 3 + ky) * 3 + kx] * in[ic][yy + ky][xx + kx];
                mx = fmaxf(mx, acc);
            }
        outp.h[oc] = (_Float16)fmaxf(mx, 0.f);
    }
    floatx4* dst = (floatx4*)(h1 + ((size_t)idx) * 32);
#pragma unroll
    for (int c = 0; c < 4; ++c) dst[c] = outp.v[c];
}

// ===========================================================================
// weight repack for conv2 MFMA: wrep[tap][nt][lane][j] = w2[oc][ic][tap]
// ===========================================================================
__global__ void __launch_bounds__(256) wrepack_kernel(const float* __restrict__ w2,
                                                      _Float16* __restrict__ wrep) {
    int idx = blockIdx.x * 256 + threadIdx.x;   // 18432
    if (idx < 18432) {
        int j = idx & 7;
        int lane = (idx >> 3) & 63;
        int nt = (idx >> 9) & 3;
        int tap = idx >> 11;
        int oc = nt * 16 + (lane & 15);
        int ic = (lane >> 4) * 8 + j;
        wrep[idx] = (_Float16)w2[(oc * 32 + ic) * 9 + tap];
    }
}

// ===========================================================================
// conv2 (32->64, 3x3 SAME) + ReLU + 64x64 avg-pool partials — implicit GEMM
// via mfma_f32_16x16x32_f16.
// ===========================================================================
__global__ void __launch_bounds__(256) conv2_mfma(const _Float16* __restrict__ h1,
                                                  const half8* __restrict__ wrep,
                                                  const float* __restrict__ c2b,
                                                  float* __restrict__ sacc) {
    __shared__ _Float16 tile[18 * 34 * 32];     // [row][px][ic] 39,168 B
    __shared__ float lsum[64];
    const int blk = blockIdx.x;                 // b*128 + yt*8 + xt
    const int b  = blk >> 7;
    const int yt = (blk >> 3) & 15;
    const int xt = blk & 7;
    const int y0 = yt * 16, x0 = xt * 32;
    const int t = threadIdx.x;
    if (t < 64) lsum[t] = 0.f;

    for (int c = t; c < 18 * 136; c += 256) {
        int row = c / 136;
        int chunk = c - row * 136;
        int gy = y0 - 1 + row;
        int px = chunk >> 2;
        int gx = x0 - 1 + px;
        floatx4 v = {0.f, 0.f, 0.f, 0.f};
        if ((unsigned)gy < 256u && (unsigned)gx < 256u)
            v = *(const floatx4*)(h1 + (((size_t)(b * 256 + gy)) * 256 + gx) * 32 + (chunk & 3) * 8);
        *(floatx4*)(tile + (row * 34 + px) * 32 + (chunk & 3) * 8) = v;
    }
    __syncthreads();

    const int w = t >> 6, lane = t & 63;
    const int q = lane >> 4, ln15 = lane & 15;
    float bias[4];
#pragma unroll
    for (int nt = 0; nt < 4; ++nt) bias[nt] = c2b[nt * 16 + ln15];
    float partial[4] = {0.f, 0.f, 0.f, 0.f};

#pragma unroll 1
    for (int gr = 0; gr < 2; ++gr) {
        floatx4 acc[4][4];
#pragma unroll
        for (int mt = 0; mt < 4; ++mt)
#pragma unroll
            for (int nt = 0; nt < 4; ++nt)
                acc[mt][nt] = floatx4{bias[nt], bias[nt], bias[nt], bias[nt]};
#pragma unroll 1
        for (int tap = 0; tap < 9; ++tap) {
            const int ky = tap / 3, kx = tap - ky * 3;
            half8 Bf[4];
#pragma unroll
            for (int nt = 0; nt < 4; ++nt) Bf[nt] = wrep[(tap * 4 + nt) * 64 + lane];
#pragma unroll
            for (int mt = 0; mt < 4; ++mt) {
                int r = w * 4 + gr * 2 + (mt >> 1);
                int xh = mt & 1;
                half8 Af = *(const half8*)(tile + ((r + ky) * 34 + xh * 16 + ln15 + kx) * 32 + q * 8);
#pragma unroll
                for (int nt = 0; nt < 4; ++nt)
                    acc[mt][nt] = __builtin_amdgcn_mfma_f32_16x16x32_f16(Af, Bf[nt], acc[mt][nt], 0, 0, 0);
            }
        }
#pragma unroll
        for (int mt = 0; mt < 4; ++mt)
#pragma unroll
            for (int nt = 0; nt < 4; ++nt)
#pragma unroll
                for (int rg = 0; rg < 4; ++rg)
                    partial[nt] += fmaxf(acc[mt][nt][rg], 0.f);
    }

#pragma unroll
    for (int nt = 0; nt < 4; ++nt) {
        float v = partial[nt];
        v += __shfl_xor(v, 16);
        v += __shfl_xor(v, 32);
        if (lane < 16) atomicAdd(&lsum[nt * 16 + ln15], v);
    }
    __syncthreads();
    const int cell = (yt >> 2) * 4 + (xt >> 1);
    if (t < 64) atomicAdd(&sacc[(((b << 6) + t) << 4) + cell], lsum[t]);
}

// ===========================================================================
__global__ void __launch_bounds__(64) finalize_phase(const float* __restrict__ psum,
                                                     const float* __restrict__ psumsq,
                                                     const unsigned* __restrict__ phist,
                                                     float* __restrict__ comb,
                                                     float* __restrict__ dout) {
    int t = threadIdx.x;
    if (t < 16) {
        const float N = 262144.f;
        float s = psum[t];
        float mean = s / N;
        float var = (psumsq[t] - s * s / N) / (N - 1.f);
        float sd = sqrtf(fmaxf(var, 0.f));
        float ent = 0.f;
        for (int i = 0; i < 64; ++i) {
            float p = (float)phist[t * 64 + i] / N;
            ent -= p * logf(p + 1e-10f);
        }
        dout[17408 + t * 3 + 0] = mean;
        dout[17408 + t * 3 + 1] = sd;
        dout[17408 + t * 3 + 2] = ent;
        float* cb = comb + t * 1091 + 1088;
        cb[0] = mean; cb[1] = sd; cb[2] = ent;
    }
}

// ===========================================================================
__global__ void __launch_bounds__(256) finalize_spatial(const float* __restrict__ sacc,
                                                        float* __restrict__ comb,
                                                        float* __restrict__ dout) {
    int idx = blockIdx.x * 256 + threadIdx.x;     // 16384
    int b = idx >> 10, j = idx & 1023;
    float v = sacc[idx] * (1.0f / 4096.0f);
    dout[1024 + idx] = v;
    comb[b * 1091 + 64 + j] = v;
}

// ===========================================================================
// fc1: [16,1091] @ W1^T -> relu -> [16,512]
// wave per (b,o): lanes sweep the CONTIGUOUS weight row (coalesced), then
// shuffle-reduce. 2048 blocks x 4 waves = 8192 dots.
// ===========================================================================
__global__ void __launch_bounds__(256) fc1_kernel(const float* __restrict__ comb,
                                                  const float* __restrict__ W1,
                                                  const float* __restrict__ B1,
                                                  float* __restrict__ out1) {
    const int wid = blockIdx.x * 4 + (threadIdx.x >> 6);  // 0..8191
    const int lane = threadIdx.x & 63;
    const int b = wid >> 9, o = wid & 511;
    const float* w = W1 + (size_t)o * 1091;
    const float* c = comb + b * 1091;
    float acc = 0.f;
#pragma unroll 4
    for (int i = 0; i < 17; ++i) {
        int k = i * 64 + lane;
        acc += w[k] * c[k];                     // 17*64 = 1088
    }
    if (lane < 3) acc += w[1088 + lane] * c[1088 + lane];
#pragma unroll
    for (int off = 32; off > 0; off >>= 1) acc += __shfl_down(acc, off);
    if (lane == 0) out1[b * 512 + o] = fmaxf(acc + B1[o], 0.f);
}

// ===========================================================================
// fc2: [16,512] @ W2^T -> z[16,128]   (wave per (b,t), coalesced row reads)
// ===========================================================================
__global__ void __launch_bounds__(256) fc2_kernel(const float* __restrict__ out1,
                                                  const float* __restrict__ W2,
                                                  const float* __restrict__ B2,
                                                  float* __restrict__ z) {
    const int wid = blockIdx.x * 4 + (threadIdx.x >> 6);  // 0..2047
    const int lane = threadIdx.x & 63;
    const int b = wid >> 7, o = wid & 127;
    const float* w = W2 + (size_t)o * 512;
    const float* c = out1 + b * 512;
    float acc = 0.f;
#pragma unroll
    for (int i = 0; i < 8; ++i) {
        int k = i * 64 + lane;
        acc += w[k] * c[k];
    }
#pragma unroll
    for (int off = 32; off > 0; off >>= 1) acc += __shfl_down(acc, off);
    if (lane == 0) z[b * 128 + o] = acc + B2[o];
}

// ===========================================================================
// layernorm over z[16,128] -> holo
// ===========================================================================
__global__ void __launch_bounds__(128) ln_kernel(const float* __restrict__ z,
                                                 const float* __restrict__ g,
                                                 const float* __restrict__ beta,
                                                 float* __restrict__ dout) {
    __shared__ float red[4];
    const int b = blockIdx.x, t = threadIdx.x;
    float acc = z[b * 128 + t];
    float s = acc;
    for (int off = 32; off > 0; off >>= 1) s += __shfl_down(s, off);
    if ((t & 63) == 0) red[t >> 6] = s;
    __syncthreads();
    float mu = (red[0] + red[1]) * (1.0f / 128.0f);
    float d = acc - mu;
    float q = d * d;
    for (int off = 32; off > 0; off >>= 1) q += __shfl_down(q, off);
    if ((t & 63) == 0) red[2 + (t >> 6)] = q;
    __syncthreads();
    float var = (red[2] + red[3]) * (1.0f / 128.0f);
    dout[17456 + b * 128 + t] = d / sqrtf(var + 1e-5f) * g[t] + beta[t];
}

// ===========================================================================
// launcher
// ===========================================================================
extern "C" void kernel_launch(void* const* d_in, const int* in_sizes, int n_in,
                              void* d_out, int out_size, void* d_ws, size_t ws_size,
                              hipStream_t stream) {
    const float* img = (const float*)d_in[0];
    const float* rec = (const float*)d_in[1];
    const float* w1  = (const float*)d_in[2];
    const float* c1b = (const float*)d_in[3];
    const float* w2  = (const float*)d_in[4];
    const float* c2b = (const float*)d_in[5];
    const float* fw1 = (const float*)d_in[6];
    const float* fb1 = (const float*)d_in[7];
    const float* fw2 = (const float*)d_in[8];
    const float* fb2 = (const float*)d_in[9];
    const float* lng = (const float*)d_in[10];
    const float* lnb = (const float*)d_in[11];
    float* out = (float*)d_out;

    float* ws = (float*)d_ws;
    float2* rowfft = (float2*)ws;                 // region0 (later grad)
    float* grad    = ws;                          // alias (rowfft dead after fft_cols)
    float* magT    = ws + OFF_BIG;                // region1
    _Float16* h1   = (_Float16*)(ws + OFF_BIG);   // alias (magT dead after collect) NHWC
    float* small_  = ws + OFF_SMALL;
    float* sacc    = small_;                      // 16384
    float* psum    = small_ + 16384;              // 16
    float* psumsq  = small_ + 16400;              // 16
    unsigned* phist = (unsigned*)(small_ + 16416);// 1024
    unsigned* mhist = (unsigned*)(small_ + 17440);// 65536
    unsigned* ccnt  = (unsigned*)(small_ + 82976);// 16    (zeroed range ends at 82992)
    int* selbin    = (int*)(small_ + 82992);      // 16
    float* dom     = small_ + 83008;              // 2048
    float* comb    = small_ + 85056;              // 17456
    float* out1    = small_ + 102512;             // 8192
    _Float16* wrep = (_Float16*)(small_ + 110704);// 18432 f16 = 9216 dwords
    float2* twg    = (float2*)(small_ + 119920);  // 512 float2 = 1024 dwords
    float* cand    = small_ + 120944;             // 16*4096 = 65536 dwords
    float* zbuf    = cand;                        // alias (cand dead after sort)

    zero_kernel<<<325, 256, 0, stream>>>(sacc, 82992);
    twiddle_init<<<2, 256, 0, stream>>>(twg);
    wrepack_kernel<<<72, 256, 0, stream>>>(w2, wrep);
    fft_rows<<<8192, 256, 0, stream>>>(img, twg, rowfft);
    fft_cols<<<1024, 256, 0, stream>>>(rowfft, twg, magT, psum, psumsq, phist);
    mag_hist<<<256, 256, 0, stream>>>(magT, mhist);
    thresh_kernel<<<16, 256, 0, stream>>>(mhist, selbin);
    collect_kernel<<<256, 256, 0, stream>>>(magT, selbin, cand, ccnt);
    sort_kernel<<<16, 1024, 0, stream>>>(cand, ccnt, dom);
    sims_kernel<<<1, 256, 0, stream>>>(dom, rec, comb, out);
    grad_kernel<<<16384, 256, 0, stream>>>(img, grad);
    conv1_pool<<<4096, 256, 0, stream>>>(grad, w1, c1b, h1);
    conv2_mfma<<<2048, 256, 0, stream>>>(h1, (const half8*)wrep, c2b, sacc);
    finalize_phase<<<1, 64, 0, stream>>>(psum, psumsq, phist, comb, out);
    finalize_spatial<<<64, 256, 0, stream>>>(sacc, comb, out);
    fc1_kernel<<<2048, 256, 0, stream>>>(comb, fw1, fb1, out1);
    fc2_kernel<<<512, 256, 0, stream>>>(out1, fw2, fb2, zbuf);
    ln_kernel<<<16, 128, 0, stream>>>(zbuf, lng, lnb, out);
}

// Round 5
// 358.840 us; speedup vs baseline: 5.3177x; 1.0533x over previous
//
#include <hip/hip_runtime.h>
#include <hip/hip_fp16.h>
#include <math.h>

// ---------------------------------------------------------------------------
// HolographicPatternExtractor  (B=16, C=1, H=W=512)
//  outputs (flat f32): sims[16,64] | spatial[16,1024] | phase_feats[16,3] | holo[16,128]
// ---------------------------------------------------------------------------

#define PI_F 3.14159274f          // float(np.pi)
#define TWO_PI_F 6.28318548f

typedef _Float16 half8 __attribute__((ext_vector_type(8)));
typedef _Float16 h2v   __attribute__((ext_vector_type(2)));
typedef float floatx4 __attribute__((ext_vector_type(4)));

// ---- workspace layout (dword offsets) ----
#define OFF_BIG   8388608
#define OFF_SMALL 25165824

// ===========================================================================
__global__ void __launch_bounds__(256) zero_kernel(float* p, int n) {
    int i = blockIdx.x * 256 + threadIdx.x;
    if (i < n) p[i] = 0.0f;
}

// ===========================================================================
// twiddle table: tw[half+p] = exp(-i*pi*p/half)
// ===========================================================================
__global__ void __launch_bounds__(256) twiddle_init(float2* __restrict__ tw) {
    int i = blockIdx.x * 256 + threadIdx.x;
    if (i < 512) {
        if (i == 0) { tw[0] = make_float2(1.f, 0.f); return; }
        int h = 31 - __clz(i);
        int H = 1 << h;
        float sn, cs;
        sincosf(-PI_F * (float)(i - H) / (float)H, &sn, &cs);
        tw[i] = make_float2(cs, sn);
    }
}

// ===========================================================================
// FFT row pass (DIF, natural input order, bit-reversed output order — OK:
// all consumers are order-invariant). One 512-pt FFT per block.
// ===========================================================================
__global__ void __launch_bounds__(256) fft_rows(const float* __restrict__ img,
                                                const float2* __restrict__ twg,
                                                float2* __restrict__ rowfft) {
    __shared__ float2 s[512];
    __shared__ float2 tw[512];
    const int t = threadIdx.x;
    const int row = blockIdx.x;                 // b*512 + y
    const float* x = img + (long long)row * 512;

    for (int i = t; i < 512; i += 256) tw[i] = twg[i];
    for (int i = t; i < 512; i += 256) s[i] = make_float2(x[i], 0.f);
    __syncthreads();
#pragma unroll
    for (int st = 9; st >= 1; --st) {
        const int half = 1 << (st - 1);
        const int pos = t & (half - 1);
        const int grp = t >> (st - 1);
        const int i1 = (grp << st) + pos;
        const int i2 = i1 + half;
        float2 w = tw[half + pos];
        float2 a = s[i1], b = s[i2];
        float dx = a.x - b.x, dy = a.y - b.y;
        s[i1] = make_float2(a.x + b.x, a.y + b.y);
        s[i2] = make_float2(dx * w.x - dy * w.y, dx * w.y + dy * w.x);
        __syncthreads();
    }
    for (int i = t; i < 512; i += 256) rowfft[(long long)row * 512 + i] = s[i];
}

// ===========================================================================
// FFT column pass (DIF): 8 columns per block; fuse magnitude (transposed
// store) + phase statistics (sum, sumsq, 64-bin histogram)
// ===========================================================================
__global__ void __launch_bounds__(256) fft_cols(const float2* __restrict__ rowfft,
                                                const float2* __restrict__ twg,
                                                float* __restrict__ magT,
                                                float* __restrict__ psum,
                                                float* __restrict__ psumsq,
                                                unsigned* __restrict__ phist) {
    __shared__ float2 s[8 * 512];               // column c contiguous at c*512
    __shared__ float2 tw[512];
    __shared__ unsigned ph[64];
    __shared__ float red[8];
    const int t = threadIdx.x;
    const int b = blockIdx.x >> 6;
    const int x0 = (blockIdx.x & 63) * 8;

    for (int i = t; i < 512; i += 256) tw[i] = twg[i];
    if (t < 64) ph[t] = 0u;
    for (int idx = t; idx < 8 * 512; idx += 256) {
        int y = idx >> 3;
        int c = idx & 7;
        s[c * 512 + y] = rowfft[((long long)(b * 512 + y)) * 512 + x0 + c];
    }
    __syncthreads();

    const int c = t >> 5;                       // 8 columns x 32 threads
    const int j0 = t & 31;
    float2* sc = s + c * 512;
#pragma unroll
    for (int st = 9; st >= 1; --st) {
        const int half = 1 << (st - 1);
#pragma unroll
        for (int k = 0; k < 8; ++k) {
            int j = j0 + (k << 5);
            int pos = j & (half - 1);
            int grp = j >> (st - 1);
            int i1 = (grp << st) + pos;
            int i2 = i1 + half;
            float2 w = tw[half + pos];
            float2 a = sc[i1], bb = sc[i2];
            float dx = a.x - bb.x, dy = a.y - bb.y;
            sc[i1] = make_float2(a.x + bb.x, a.y + bb.y);
            sc[i2] = make_float2(dx * w.x - dy * w.y, dx * w.y + dy * w.x);
        }
        __syncthreads();
    }

    float lsum = 0.f, lsq = 0.f;
    for (int idx = t; idx < 8 * 512; idx += 256) {
        int cc = idx >> 9;
        int y = idx & 511;
        float2 v = s[cc * 512 + y];
        float mag = sqrtf(v.x * v.x + v.y * v.y);
        magT[((long long)(b * 512 + x0 + cc)) * 512 + y] = mag;
        float phv = atan2f(v.y, v.x);
        lsum += phv;
        lsq += phv * phv;
        int bin = (int)floorf((phv + PI_F) / TWO_PI_F * 64.0f);
        bin = min(max(bin, 0), 63);
        atomicAdd(&ph[bin], 1u);
    }
    for (int off = 32; off > 0; off >>= 1) {
        lsum += __shfl_down(lsum, off);
        lsq  += __shfl_down(lsq, off);
    }
    if ((t & 63) == 0) { red[t >> 6] = lsum; red[4 + (t >> 6)] = lsq; }
    __syncthreads();
    if (t == 0) {
        atomicAdd(psum + b,   red[0] + red[1] + red[2] + red[3]);
        atomicAdd(psumsq + b, red[4] + red[5] + red[6] + red[7]);
    }
    if (t < 64 && ph[t]) atomicAdd(&phist[b * 64 + t], ph[t]);
}

// ===========================================================================
// magnitude histogram for top-k threshold (bits>>19 monotone for mag>=0)
// ===========================================================================
__global__ void __launch_bounds__(256) mag_hist(const float* __restrict__ magT,
                                                unsigned* __restrict__ mhist) {
    __shared__ unsigned h[4096];
    for (int i = threadIdx.x; i < 4096; i += 256) h[i] = 0u;
    __syncthreads();
    int b = blockIdx.x >> 4;
    int chunk = blockIdx.x & 15;
    const float* m = magT + (long long)b * 262144 + chunk * 16384;
    for (int i = threadIdx.x; i < 16384; i += 256) {
        unsigned bits = __float_as_uint(m[i]);
        unsigned bin = min(bits >> 19, 4095u);
        atomicAdd(&h[bin], 1u);
    }
    __syncthreads();
    for (int i = threadIdx.x; i < 4096; i += 256)
        if (h[i]) atomicAdd(&mhist[b * 4096 + i], h[i]);
}

// ===========================================================================
// top-k: threshold bin from histogram suffix-count
// ===========================================================================
__global__ void __launch_bounds__(256) thresh_kernel(const unsigned* __restrict__ mhist,
                                                     int* __restrict__ selbin) {
    __shared__ unsigned csum[256];
    const int b = blockIdx.x, t = threadIdx.x;
    unsigned s = 0;
    for (int i = 0; i < 16; ++i) s += mhist[b * 4096 + t * 16 + i];
    csum[t] = s;
    __syncthreads();
    if (t == 0) {
        unsigned acc = 0; int chunk = 0;
        for (int i = 255; i >= 0; --i) {
            acc += csum[i];
            if (acc >= 128u) { chunk = i; break; }
        }
        unsigned acc2 = acc - csum[chunk];      // count strictly above chunk
        int tb = chunk * 16;
        for (int i = chunk * 16 + 15; i >= chunk * 16; --i) {
            acc2 += mhist[b * 4096 + i];
            if (acc2 >= 128u) { tb = i; break; }
        }
        selbin[b] = tb;
    }
}

// ===========================================================================
// top-k: parallel candidate collection (256 blocks)
// ===========================================================================
#define TK_CAP 4096
__global__ void __launch_bounds__(256) collect_kernel(const float* __restrict__ magT,
                                                      const int* __restrict__ selbin,
                                                      float* __restrict__ cand,
                                                      unsigned* __restrict__ ccnt) {
    const int blk = blockIdx.x;
    const int b = blk >> 4, chunk = blk & 15;
    const unsigned tb = (unsigned)selbin[b];
    const floatx4* m = (const floatx4*)(magT + (long long)b * 262144 + chunk * 16384);
    float* cb = cand + b * TK_CAP;
    for (int i = threadIdx.x; i < 4096; i += 256) {
        floatx4 v = m[i];
#pragma unroll
        for (int k = 0; k < 4; ++k) {
            float x = v[k];
            unsigned bin = min(__float_as_uint(x) >> 19, 4095u);
            if (bin >= tb) {
                unsigned p = atomicAdd(&ccnt[b], 1u);
                if (p < TK_CAP) cb[p] = x;
            }
        }
    }
}

// ===========================================================================
// top-k: bitonic sort descending of candidates -> dom[b][128]
// ===========================================================================
__global__ void __launch_bounds__(1024) sort_kernel(const float* __restrict__ cand,
                                                    const unsigned* __restrict__ ccnt,
                                                    float* __restrict__ dom) {
    __shared__ float c[TK_CAP];
    const int b = blockIdx.x, t = threadIdx.x;
    const unsigned n = min(ccnt[b], (unsigned)TK_CAP);
    int P = 256;
    while (P < (int)n) P <<= 1;                 // 256..4096
    for (int i = t; i < P; i += 1024) c[i] = (i < (int)n) ? cand[b * TK_CAP + i] : -1.0f;
    __syncthreads();
    for (int k = 2; k <= P; k <<= 1) {
        for (int j = k >> 1; j > 0; j >>= 1) {
            for (int i = t; i < P; i += 1024) {
                int ixj = i ^ j;
                if (ixj > i) {
                    float a = c[i], d = c[ixj];
                    bool up = ((i & k) == 0);
                    if (up ? (a < d) : (a > d)) { c[i] = d; c[ixj] = a; }
                }
            }
            __syncthreads();
        }
    }
    if (t < 128) dom[b * 128 + t] = c[t];
}

// ===========================================================================
// sims = normalize(dom) @ normalize(receptors)^T
// ===========================================================================
__global__ void __launch_bounds__(256) sims_kernel(const float* __restrict__ dom,
                                                   const float* __restrict__ rec,
                                                   float* __restrict__ comb,
                                                   float* __restrict__ dout) {
    __shared__ float sd[16 * 128];
    __shared__ float sr[64 * 128];
    __shared__ float scale[80];
    const int t = threadIdx.x;
    for (int i = t; i < 2048; i += 256) sd[i] = dom[i];
    for (int i = t; i < 8192; i += 256) sr[i] = rec[i];
    __syncthreads();
    if (t < 80) {
        const float* base = (t < 16) ? (sd + t * 128) : (sr + (t - 16) * 128);
        float s = 0.f;
        for (int k = 0; k < 128; ++k) s += base[k] * base[k];
        scale[t] = 1.0f / fmaxf(sqrtf(s), 1e-12f);
    }
    __syncthreads();
    for (int o = t; o < 1024; o += 256) {
        int b = o >> 6, p = o & 63;
        const float* dv = sd + b * 128;
        const float* rv = sr + p * 128;
        float s = 0.f;
        for (int k = 0; k < 128; ++k) s += dv[k] * rv[k];
        float val = s * scale[b] * scale[16 + p];
        dout[b * 64 + p] = val;
        comb[b * 1091 + p] = val;
    }
}

// ===========================================================================
// FUSED gradient + conv1 (2->32, 3x3 SAME) + ReLU + maxpool2 -> h1 NHWC fp16
// Block = 16x16 pooled tile. img 36x36 staged in LDS, gmag/gori computed
// in-LDS as duplicated-pair half2 ([x, x+1]) so the two maxpool x-positions
// ride v_pk_fma_f16 halves (2x fp32 FMA rate).
// ===========================================================================
__global__ void __launch_bounds__(256) grad_conv1(const float* __restrict__ img,
                                                  const h2v* __restrict__ w1h2,
                                                  const float* __restrict__ c1b,
                                                  _Float16* __restrict__ h1) {
    __shared__ float simg[36 * 37];
    __shared__ _Float16 smag2[35 * 36 * 2];   // half2 pairs [row][p] = (mag[p], mag[p+1])
    __shared__ _Float16 sori2[35 * 36 * 2];
    const int blk = blockIdx.x;               // b*256 + tile
    const int b = blk >> 8;
    const int tr = blk & 255;
    const int ty0 = (tr >> 4) * 16, tx0 = (tr & 15) * 16;
    const int t = threadIdx.x;
    const float* im = img + (long long)b * 262144;
    const int iy0 = 2 * ty0 - 2, ix0 = 2 * tx0 - 2;

    // ---- stage img 36x36 (clamped coords; out-of-image grad zeroed later) --
    for (int idx = t; idx < 1296; idx += 256) {
        int iy = idx / 36, ix = idx - iy * 36;
        int gy = min(max(iy0 + iy, 0), 511);
        int gx = min(max(ix0 + ix, 0), 511);
        simg[iy * 37 + ix] = im[gy * 512 + gx];
    }
    __syncthreads();

    // ---- gradient tile: 35 rows x 36 cols, duplicated-pair half2 stores ----
    for (int idx = t; idx < 1260; idx += 256) {
        int iy = idx / 36, ix = idx - iy * 36;       // grad-local coords
        int gy = 2 * ty0 - 1 + iy, gx = 2 * tx0 - 1 + ix;
        float up = simg[iy * 37 + ix + 1];
        float dn = simg[(iy + 2) * 37 + ix + 1];
        float lf = simg[(iy + 1) * 37 + ix];
        float rt = simg[(iy + 1) * 37 + ix + 2];
        float fy = (gy <= 0 || gy >= 511) ? 1.f : 0.5f;
        float fx = (gx <= 0 || gx >= 511) ? 1.f : 0.5f;
        float gyv = (dn - up) * fy, gxv = (rt - lf) * fx;
        bool inside = ((unsigned)gy < 512u) && ((unsigned)gx < 512u);
        float mag = inside ? sqrtf(gxv * gxv + gyv * gyv) : 0.f;
        float ori = inside ? atan2f(gyv, gxv) : 0.f;
        _Float16 hm = (_Float16)mag, ho = (_Float16)ori;
        if (ix < 35) {
            smag2[(iy * 36 + ix) * 2]     = hm;
            sori2[(iy * 36 + ix) * 2]     = ho;
        }
        if (ix > 0) {
            smag2[(iy * 36 + ix - 1) * 2 + 1] = hm;
            sori2[(iy * 36 + ix - 1) * 2 + 1] = ho;
        }
    }
    __syncthreads();

    // ---- conv + relu + maxpool: thread = pooled pixel --------------------
    const int ly = t >> 4, lx = t & 15;
    h2v inm[5][3], ino[5][3];
#pragma unroll
    for (int dy = 0; dy < 5; ++dy)
#pragma unroll
        for (int kx = 0; kx < 3; ++kx) {
            int p = (2 * ly + dy) * 36 + 2 * lx + kx;
            inm[dy][kx] = *(const h2v*)(smag2 + p * 2);
            ino[dy][kx] = *(const h2v*)(sori2 + p * 2);
        }

    union { _Float16 h[32]; floatx4 v[4]; } outp;
#pragma unroll 4
    for (int oc = 0; oc < 32; ++oc) {
        _Float16 hb = (_Float16)c1b[oc];
        h2v acc0 = {hb, hb}, acc1 = {hb, hb};
#pragma unroll
        for (int ky = 0; ky < 3; ++ky)
#pragma unroll
            for (int kx = 0; kx < 3; ++kx) {
                h2v wm = w1h2[oc * 18 + ky * 3 + kx];
                h2v wo = w1h2[oc * 18 + 9 + ky * 3 + kx];
                acc0 += wm * inm[ky][kx];
                acc1 += wm * inm[1 + ky][kx];
                acc0 += wo * ino[ky][kx];
                acc1 += wo * ino[1 + ky][kx];
            }
        float m = fmaxf(fmaxf((float)acc0[0], (float)acc0[1]),
                        fmaxf((float)acc1[0], (float)acc1[1]));
        outp.h[oc] = (_Float16)fmaxf(m, 0.f);
    }
    const int py = ty0 + ly, px = tx0 + lx;
    floatx4* dst = (floatx4*)(h1 + (((size_t)b * 65536) + py * 256 + px) * 32);
#pragma unroll
    for (int c = 0; c < 4; ++c) dst[c] = outp.v[c];
}

// ===========================================================================
// weight repacks: conv2 MFMA B-fragments + conv1 half2-broadcast weights
// ===========================================================================
__global__ void __launch_bounds__(256) wrepack_kernel(const float* __restrict__ w2,
                                                      const float* __restrict__ w1,
                                                      _Float16* __restrict__ wrep,
                                                      _Float16* __restrict__ w1h2) {
    int idx = blockIdx.x * 256 + threadIdx.x;   // 18432
    if (idx < 18432) {
        int j = idx & 7;
        int lane = (idx >> 3) & 63;
        int nt = (idx >> 9) & 3;
        int tap = idx >> 11;
        int oc = nt * 16 + (lane & 15);
        int ic = (lane >> 4) * 8 + j;
        wrep[idx] = (_Float16)w2[(oc * 32 + ic) * 9 + tap];
    }
    if (idx < 576) {
        _Float16 w = (_Float16)w1[idx];
        w1h2[idx * 2] = w;
        w1h2[idx * 2 + 1] = w;
    }
}

// ===========================================================================
// conv2 (32->64, 3x3 SAME) + ReLU + 64x64 avg-pool partials — implicit GEMM
// via mfma_f32_16x16x32_f16.
// ===========================================================================
__global__ void __launch_bounds__(256) conv2_mfma(const _Float16* __restrict__ h1,
                                                  const half8* __restrict__ wrep,
                                                  const float* __restrict__ c2b,
                                                  float* __restrict__ sacc) {
    __shared__ _Float16 tile[18 * 34 * 32];     // [row][px][ic] 39,168 B
    __shared__ float lsum[64];
    const int blk = blockIdx.x;                 // b*128 + yt*8 + xt
    const int b  = blk >> 7;
    const int yt = (blk >> 3) & 15;
    const int xt = blk & 7;
    const int y0 = yt * 16, x0 = xt * 32;
    const int t = threadIdx.x;
    if (t < 64) lsum[t] = 0.f;

    for (int c = t; c < 18 * 136; c += 256) {
        int row = c / 136;
        int chunk = c - row * 136;
        int gy = y0 - 1 + row;
        int px = chunk >> 2;
        int gx = x0 - 1 + px;
        floatx4 v = {0.f, 0.f, 0.f, 0.f};
        if ((unsigned)gy < 256u && (unsigned)gx < 256u)
            v = *(const floatx4*)(h1 + (((size_t)(b * 256 + gy)) * 256 + gx) * 32 + (chunk & 3) * 8);
        *(floatx4*)(tile + (row * 34 + px) * 32 + (chunk & 3) * 8) = v;
    }
    __syncthreads();

    const int w = t >> 6, lane = t & 63;
    const int q = lane >> 4, ln15 = lane & 15;
    float bias[4];
#pragma unroll
    for (int nt = 0; nt < 4; ++nt) bias[nt] = c2b[nt * 16 + ln15];
    float partial[4] = {0.f, 0.f, 0.f, 0.f};

#pragma unroll 1
    for (int gr = 0; gr < 2; ++gr) {
        floatx4 acc[4][4];
#pragma unroll
        for (int mt = 0; mt < 4; ++mt)
#pragma unroll
            for (int nt = 0; nt < 4; ++nt)
                acc[mt][nt] = floatx4{bias[nt], bias[nt], bias[nt], bias[nt]};
#pragma unroll 1
        for (int tap = 0; tap < 9; ++tap) {
            const int ky = tap / 3, kx = tap - ky * 3;
            half8 Bf[4];
#pragma unroll
            for (int nt = 0; nt < 4; ++nt) Bf[nt] = wrep[(tap * 4 + nt) * 64 + lane];
#pragma unroll
            for (int mt = 0; mt < 4; ++mt) {
                int r = w * 4 + gr * 2 + (mt >> 1);
                int xh = mt & 1;
                half8 Af = *(const half8*)(tile + ((r + ky) * 34 + xh * 16 + ln15 + kx) * 32 + q * 8);
#pragma unroll
                for (int nt = 0; nt < 4; ++nt)
                    acc[mt][nt] = __builtin_amdgcn_mfma_f32_16x16x32_f16(Af, Bf[nt], acc[mt][nt], 0, 0, 0);
            }
        }
#pragma unroll
        for (int mt = 0; mt < 4; ++mt)
#pragma unroll
            for (int nt = 0; nt < 4; ++nt)
#pragma unroll
                for (int rg = 0; rg < 4; ++rg)
                    partial[nt] += fmaxf(acc[mt][nt][rg], 0.f);
    }

#pragma unroll
    for (int nt = 0; nt < 4; ++nt) {
        float v = partial[nt];
        v += __shfl_xor(v, 16);
        v += __shfl_xor(v, 32);
        if (lane < 16) atomicAdd(&lsum[nt * 16 + ln15], v);
    }
    __syncthreads();
    const int cell = (yt >> 2) * 4 + (xt >> 1);
    if (t < 64) atomicAdd(&sacc[(((b << 6) + t) << 4) + cell], lsum[t]);
}

// ===========================================================================
__global__ void __launch_bounds__(64) finalize_phase(const float* __restrict__ psum,
                                                     const float* __restrict__ psumsq,
                                                     const unsigned* __restrict__ phist,
                                                     float* __restrict__ comb,
                                                     float* __restrict__ dout) {
    int t = threadIdx.x;
    if (t < 16) {
        const float N = 262144.f;
        float s = psum[t];
        float mean = s / N;
        float var = (psumsq[t] - s * s / N) / (N - 1.f);
        float sd = sqrtf(fmaxf(var, 0.f));
        float ent = 0.f;
        for (int i = 0; i < 64; ++i) {
            float p = (float)phist[t * 64 + i] / N;
            ent -= p * logf(p + 1e-10f);
        }
        dout[17408 + t * 3 + 0] = mean;
        dout[17408 + t * 3 + 1] = sd;
        dout[17408 + t * 3 + 2] = ent;
        float* cb = comb + t * 1091 + 1088;
        cb[0] = mean; cb[1] = sd; cb[2] = ent;
    }
}

// ===========================================================================
__global__ void __launch_bounds__(256) finalize_spatial(const float* __restrict__ sacc,
                                                        float* __restrict__ comb,
                                                        float* __restrict__ dout) {
    int idx = blockIdx.x * 256 + threadIdx.x;     // 16384
    int b = idx >> 10, j = idx & 1023;
    float v = sacc[idx] * (1.0f / 4096.0f);
    dout[1024 + idx] = v;
    comb[b * 1091 + 64 + j] = v;
}

// ===========================================================================
// fc1: wave per (b,o), coalesced weight-row sweep + shuffle reduce
// ===========================================================================
__global__ void __launch_bounds__(256) fc1_kernel(const float* __restrict__ comb,
                                                  const float* __restrict__ W1,
                                                  const float* __restrict__ B1,
                                                  float* __restrict__ out1) {
    const int wid = blockIdx.x * 4 + (threadIdx.x >> 6);  // 0..8191
    const int lane = threadIdx.x & 63;
    const int b = wid >> 9, o = wid & 511;
    const float* w = W1 + (size_t)o * 1091;
    const float* c = comb + b * 1091;
    float acc = 0.f;
#pragma unroll 4
    for (int i = 0; i < 17; ++i) {
        int k = i * 64 + lane;
        acc += w[k] * c[k];                     // 17*64 = 1088
    }
    if (lane < 3) acc += w[1088 + lane] * c[1088 + lane];
#pragma unroll
    for (int off = 32; off > 0; off >>= 1) acc += __shfl_down(acc, off);
    if (lane == 0) out1[b * 512 + o] = fmaxf(acc + B1[o], 0.f);
}

// ===========================================================================
// fc2: wave per (b,o)
// ===========================================================================
__global__ void __launch_bounds__(256) fc2_kernel(const float* __restrict__ out1,
                                                  const float* __restrict__ W2,
                                                  const float* __restrict__ B2,
                                                  float* __restrict__ z) {
    const int wid = blockIdx.x * 4 + (threadIdx.x >> 6);  // 0..2047
    const int lane = threadIdx.x & 63;
    const int b = wid >> 7, o = wid & 127;
    const float* w = W2 + (size_t)o * 512;
    const float* c = out1 + b * 512;
    float acc = 0.f;
#pragma unroll
    for (int i = 0; i < 8; ++i) {
        int k = i * 64 + lane;
        acc += w[k] * c[k];
    }
#pragma unroll
    for (int off = 32; off > 0; off >>= 1) acc += __shfl_down(acc, off);
    if (lane == 0) z[b * 128 + o] = acc + B2[o];
}

// ===========================================================================
// layernorm over z[16,128] -> holo
// ===========================================================================
__global__ void __launch_bounds__(128) ln_kernel(const float* __restrict__ z,
                                                 const float* __restrict__ g,
                                                 const float* __restrict__ beta,
                                                 float* __restrict__ dout) {
    __shared__ float red[4];
    const int b = blockIdx.x, t = threadIdx.x;
    float acc = z[b * 128 + t];
    float s = acc;
    for (int off = 32; off > 0; off >>= 1) s += __shfl_down(s, off);
    if ((t & 63) == 0) red[t >> 6] = s;
    __syncthreads();
    float mu = (red[0] + red[1]) * (1.0f / 128.0f);
    float d = acc - mu;
    float q = d * d;
    for (int off = 32; off > 0; off >>= 1) q += __shfl_down(q, off);
    if ((t & 63) == 0) red[2 + (t >> 6)] = q;
    __syncthreads();
    float var = (red[2] + red[3]) * (1.0f / 128.0f);
    dout[17456 + b * 128 + t] = d / sqrtf(var + 1e-5f) * g[t] + beta[t];
}

// ===========================================================================
// launcher
// ===========================================================================
extern "C" void kernel_launch(void* const* d_in, const int* in_sizes, int n_in,
                              void* d_out, int out_size, void* d_ws, size_t ws_size,
                              hipStream_t stream) {
    const float* img = (const float*)d_in[0];
    const float* rec = (const float*)d_in[1];
    const float* w1  = (const float*)d_in[2];
    const float* c1b = (const float*)d_in[3];
    const float* w2  = (const float*)d_in[4];
    const float* c2b = (const float*)d_in[5];
    const float* fw1 = (const float*)d_in[6];
    const float* fb1 = (const float*)d_in[7];
    const float* fw2 = (const float*)d_in[8];
    const float* fb2 = (const float*)d_in[9];
    const float* lng = (const float*)d_in[10];
    const float* lnb = (const float*)d_in[11];
    float* out = (float*)d_out;

    float* ws = (float*)d_ws;
    float2* rowfft = (float2*)ws;                 // region0
    float* magT    = ws + OFF_BIG;                // region1
    _Float16* h1   = (_Float16*)(ws + OFF_BIG);   // alias (magT dead after collect) NHWC
    float* small_  = ws + OFF_SMALL;
    float* sacc    = small_;                      // 16384
    float* psum    = small_ + 16384;              // 16
    float* psumsq  = small_ + 16400;              // 16
    unsigned* phist = (unsigned*)(small_ + 16416);// 1024
    unsigned* mhist = (unsigned*)(small_ + 17440);// 65536
    unsigned* ccnt  = (unsigned*)(small_ + 82976);// 16    (zeroed range ends at 82992)
    int* selbin    = (int*)(small_ + 82992);      // 16
    float* dom     = small_ + 83008;              // 2048
    float* comb    = small_ + 85056;              // 17456
    float* out1    = small_ + 102512;             // 8192
    _Float16* wrep = (_Float16*)(small_ + 110704);// 18432 f16 = 9216 dwords
    float2* twg    = (float2*)(small_ + 119920);  // 512 float2 = 1024 dwords
    float* cand    = small_ + 120944;             // 16*4096 = 65536 dwords
    float* zbuf    = cand;                        // alias (cand dead after sort)
    _Float16* w1h2 = (_Float16*)(small_ + 186480);// 1152 f16 = 576 dwords

    zero_kernel<<<325, 256, 0, stream>>>(sacc, 82992);
    twiddle_init<<<2, 256, 0, stream>>>(twg);
    wrepack_kernel<<<72, 256, 0, stream>>>(w2, w1, wrep, w1h2);
    fft_rows<<<8192, 256, 0, stream>>>(img, twg, rowfft);
    fft_cols<<<1024, 256, 0, stream>>>(rowfft, twg, magT, psum, psumsq, phist);
    mag_hist<<<256, 256, 0, stream>>>(magT, mhist);
    thresh_kernel<<<16, 256, 0, stream>>>(mhist, selbin);
    collect_kernel<<<256, 256, 0, stream>>>(magT, selbin, cand, ccnt);
    sort_kernel<<<16, 1024, 0, stream>>>(cand, ccnt, dom);
    sims_kernel<<<1, 256, 0, stream>>>(dom, rec, comb, out);
    grad_conv1<<<4096, 256, 0, stream>>>(img, (const h2v*)w1h2, c1b, h1);
    conv2_mfma<<<2048, 256, 0, stream>>>(h1, (const half8*)wrep, c2b, sacc);
    finalize_phase<<<1, 64, 0, stream>>>(psum, psumsq, phist, comb, out);
    finalize_spatial<<<64, 256, 0, stream>>>(sacc, comb, out);
    fc1_kernel<<<2048, 256, 0, stream>>>(comb, fw1, fb1, out1);
    fc2_kernel<<<512, 256, 0, stream>>>(out1, fw2, fb2, zbuf);
    ln_kernel<<<16, 128, 0, stream>>>(zbuf, lng, lnb, out);
}

// Round 6
// 357.439 us; speedup vs baseline: 5.3385x; 1.0039x over previous
//
#include <hip/hip_runtime.h>
#include <hip/hip_fp16.h>
#include <math.h>

// ---------------------------------------------------------------------------
// HolographicPatternExtractor  (B=16, C=1, H=W=512)
//  outputs (flat f32): sims[16,64] | spatial[16,1024] | phase_feats[16,3] | holo[16,128]
// ---------------------------------------------------------------------------

#define PI_F 3.14159274f          // float(np.pi)
#define TWO_PI_F 6.28318548f

typedef _Float16 half8 __attribute__((ext_vector_type(8)));
typedef _Float16 h2v   __attribute__((ext_vector_type(2)));
typedef float floatx4 __attribute__((ext_vector_type(4)));

// ---- workspace layout (dword offsets) ----
#define OFF_BIG   8388608
#define OFF_SMALL 25165824
#define NBIN 2048                 // magnitude histogram bins (bits>>20)

// ===========================================================================
// combined init: zero accumulators + twiddle table + weight repacks
// ===========================================================================
__global__ void __launch_bounds__(256) init_kernel(float* __restrict__ zp,
                                                   float2* __restrict__ tw,
                                                   const float* __restrict__ w2,
                                                   const float* __restrict__ w1,
                                                   _Float16* __restrict__ wrep,
                                                   _Float16* __restrict__ w1d) {
    int idx = blockIdx.x * 256 + threadIdx.x;
    if (idx < 82992) zp[idx] = 0.0f;
    if (idx < 512) {
        if (idx == 0) tw[0] = make_float2(1.f, 0.f);
        else {
            int h = 31 - __clz(idx);
            int H = 1 << h;
            float sn, cs;
            sincosf(-PI_F * (float)(idx - H) / (float)H, &sn, &cs);
            tw[idx] = make_float2(cs, sn);
        }
    }
    if (idx < 18432) {            // conv2 MFMA B-fragment
        int j = idx & 7;
        int lane = (idx >> 3) & 63;
        int nt = (idx >> 9) & 3;
        int tap = idx >> 11;
        int oc = nt * 16 + (lane & 15);
        int ic = (lane >> 4) * 8 + j;
        wrep[idx] = (_Float16)w2[(oc * 32 + ic) * 9 + tap];
    }
    if (idx < 288) {              // conv1 weights: [tap][oc] -> (wm,wm,wo,wo)
        int tap = idx >> 5, oc = idx & 31;
        _Float16 wm = (_Float16)w1[oc * 18 + tap];        // ic=0 (gmag)
        _Float16 wo = (_Float16)w1[oc * 18 + 9 + tap];    // ic=1 (gori)
        w1d[idx * 4 + 0] = wm; w1d[idx * 4 + 1] = wm;
        w1d[idx * 4 + 2] = wo; w1d[idx * 4 + 3] = wo;
    }
}

// ===========================================================================
// FFT row pass (DIF, natural input, bit-reversed output — consumers are
// order-invariant). One 512-pt FFT per block.
// ===========================================================================
__global__ void __launch_bounds__(256) fft_rows(const float* __restrict__ img,
                                                const float2* __restrict__ twg,
                                                float2* __restrict__ rowfft) {
    __shared__ float2 s[512];
    __shared__ float2 tw[512];
    const int t = threadIdx.x;
    const int row = blockIdx.x;                 // b*512 + y
    const float* x = img + (long long)row * 512;

    for (int i = t; i < 512; i += 256) tw[i] = twg[i];
    for (int i = t; i < 512; i += 256) s[i] = make_float2(x[i], 0.f);
    __syncthreads();
#pragma unroll
    for (int st = 9; st >= 1; --st) {
        const int half = 1 << (st - 1);
        const int pos = t & (half - 1);
        const int grp = t >> (st - 1);
        const int i1 = (grp << st) + pos;
        const int i2 = i1 + half;
        float2 w = tw[half + pos];
        float2 a = s[i1], b = s[i2];
        float dx = a.x - b.x, dy = a.y - b.y;
        s[i1] = make_float2(a.x + b.x, a.y + b.y);
        s[i2] = make_float2(dx * w.x - dy * w.y, dx * w.y + dy * w.x);
        __syncthreads();
    }
    for (int i = t; i < 512; i += 256) rowfft[(long long)row * 512 + i] = s[i];
}

// ===========================================================================
// FFT column pass (DIF): 8 columns/block; fused magnitude (transposed store)
// + phase stats + magnitude histogram (2048 bins, for top-k threshold)
// ===========================================================================
__global__ void __launch_bounds__(256) fft_cols(const float2* __restrict__ rowfft,
                                                const float2* __restrict__ twg,
                                                float* __restrict__ magT,
                                                float* __restrict__ psum,
                                                float* __restrict__ psumsq,
                                                unsigned* __restrict__ phist,
                                                unsigned* __restrict__ mhist) {
    __shared__ float2 s[8 * 512];               // column c contiguous at c*512
    __shared__ float2 tw[512];
    __shared__ unsigned ph[64];
    __shared__ unsigned mh[NBIN];
    __shared__ float red[8];
    const int t = threadIdx.x;
    const int b = blockIdx.x >> 6;
    const int x0 = (blockIdx.x & 63) * 8;

    for (int i = t; i < 512; i += 256) tw[i] = twg[i];
    if (t < 64) ph[t] = 0u;
    for (int i = t; i < NBIN; i += 256) mh[i] = 0u;
    for (int idx = t; idx < 8 * 512; idx += 256) {
        int y = idx >> 3;
        int c = idx & 7;
        s[c * 512 + y] = rowfft[((long long)(b * 512 + y)) * 512 + x0 + c];
    }
    __syncthreads();

    const int c = t >> 5;                       // 8 columns x 32 threads
    const int j0 = t & 31;
    float2* sc = s + c * 512;
#pragma unroll
    for (int st = 9; st >= 1; --st) {
        const int half = 1 << (st - 1);
#pragma unroll
        for (int k = 0; k < 8; ++k) {
            int j = j0 + (k << 5);
            int pos = j & (half - 1);
            int grp = j >> (st - 1);
            int i1 = (grp << st) + pos;
            int i2 = i1 + half;
            float2 w = tw[half + pos];
            float2 a = sc[i1], bb = sc[i2];
            float dx = a.x - bb.x, dy = a.y - bb.y;
            sc[i1] = make_float2(a.x + bb.x, a.y + bb.y);
            sc[i2] = make_float2(dx * w.x - dy * w.y, dx * w.y + dy * w.x);
        }
        __syncthreads();
    }

    float lsum = 0.f, lsq = 0.f;
    for (int idx = t; idx < 8 * 512; idx += 256) {
        int cc = idx >> 9;
        int y = idx & 511;
        float2 v = s[cc * 512 + y];
        float mag = sqrtf(v.x * v.x + v.y * v.y);
        magT[((long long)(b * 512 + x0 + cc)) * 512 + y] = mag;
        unsigned mb = min(__float_as_uint(mag) >> 20, (unsigned)(NBIN - 1));
        atomicAdd(&mh[mb], 1u);
        float phv = atan2f(v.y, v.x);
        lsum += phv;
        lsq += phv * phv;
        int bin = (int)floorf((phv + PI_F) / TWO_PI_F * 64.0f);
        bin = min(max(bin, 0), 63);
        atomicAdd(&ph[bin], 1u);
    }
    for (int off = 32; off > 0; off >>= 1) {
        lsum += __shfl_down(lsum, off);
        lsq  += __shfl_down(lsq, off);
    }
    if ((t & 63) == 0) { red[t >> 6] = lsum; red[4 + (t >> 6)] = lsq; }
    __syncthreads();
    if (t == 0) {
        atomicAdd(psum + b,   red[0] + red[1] + red[2] + red[3]);
        atomicAdd(psumsq + b, red[4] + red[5] + red[6] + red[7]);
    }
    if (t < 64 && ph[t]) atomicAdd(&phist[b * 64 + t], ph[t]);
    for (int i = t; i < NBIN; i += 256)
        if (mh[i]) atomicAdd(&mhist[b * NBIN + i], mh[i]);
}

// ===========================================================================
// top-k: threshold bin from histogram suffix-count
// ===========================================================================
__global__ void __launch_bounds__(256) thresh_kernel(const unsigned* __restrict__ mhist,
                                                     int* __restrict__ selbin) {
    __shared__ unsigned csum[256];
    const int b = blockIdx.x, t = threadIdx.x;
    unsigned s = 0;
    for (int i = 0; i < NBIN / 256; ++i) s += mhist[b * NBIN + t * (NBIN / 256) + i];
    csum[t] = s;
    __syncthreads();
    if (t == 0) {
        unsigned acc = 0; int chunk = 0;
        for (int i = 255; i >= 0; --i) {
            acc += csum[i];
            if (acc >= 128u) { chunk = i; break; }
        }
        unsigned acc2 = acc - csum[chunk];      // count strictly above chunk
        int tb = chunk * (NBIN / 256);
        for (int i = chunk * (NBIN / 256) + (NBIN / 256) - 1; i >= chunk * (NBIN / 256); --i) {
            acc2 += mhist[b * NBIN + i];
            if (acc2 >= 128u) { tb = i; break; }
        }
        selbin[b] = tb;
    }
}

// ===========================================================================
// top-k: parallel candidate collection (256 blocks)
// ===========================================================================
#define TK_CAP 4096
__global__ void __launch_bounds__(256) collect_kernel(const float* __restrict__ magT,
                                                      const int* __restrict__ selbin,
                                                      float* __restrict__ cand,
                                                      unsigned* __restrict__ ccnt) {
    const int blk = blockIdx.x;
    const int b = blk >> 4, chunk = blk & 15;
    const unsigned tb = (unsigned)selbin[b];
    const floatx4* m = (const floatx4*)(magT + (long long)b * 262144 + chunk * 16384);
    float* cb = cand + b * TK_CAP;
    for (int i = threadIdx.x; i < 4096; i += 256) {
        floatx4 v = m[i];
#pragma unroll
        for (int k = 0; k < 4; ++k) {
            float x = v[k];
            unsigned bin = min(__float_as_uint(x) >> 20, (unsigned)(NBIN - 1));
            if (bin >= tb) {
                unsigned p = atomicAdd(&ccnt[b], 1u);
                if (p < TK_CAP) cb[p] = x;
            }
        }
    }
}

// ===========================================================================
// top-k: bitonic sort descending of candidates -> dom[b][128]
// ===========================================================================
__global__ void __launch_bounds__(1024) sort_kernel(const float* __restrict__ cand,
                                                    const unsigned* __restrict__ ccnt,
                                                    float* __restrict__ dom) {
    __shared__ float c[TK_CAP];
    const int b = blockIdx.x, t = threadIdx.x;
    const unsigned n = min(ccnt[b], (unsigned)TK_CAP);
    int P = 256;
    while (P < (int)n) P <<= 1;                 // 256..4096
    for (int i = t; i < P; i += 1024) c[i] = (i < (int)n) ? cand[b * TK_CAP + i] : -1.0f;
    __syncthreads();
    for (int k = 2; k <= P; k <<= 1) {
        for (int j = k >> 1; j > 0; j >>= 1) {
            for (int i = t; i < P; i += 1024) {
                int ixj = i ^ j;
                if (ixj > i) {
                    float a = c[i], d = c[ixj];
                    bool up = ((i & k) == 0);
                    if (up ? (a < d) : (a > d)) { c[i] = d; c[ixj] = a; }
                }
            }
            __syncthreads();
        }
    }
    if (t < 128) dom[b * 128 + t] = c[t];
}

// ===========================================================================
// sims = normalize(dom) @ normalize(receptors)^T
// ===========================================================================
__global__ void __launch_bounds__(256) sims_kernel(const float* __restrict__ dom,
                                                   const float* __restrict__ rec,
                                                   float* __restrict__ comb,
                                                   float* __restrict__ dout) {
    __shared__ float sd[16 * 128];
    __shared__ float sr[64 * 128];
    __shared__ float scale[80];
    const int t = threadIdx.x;
    for (int i = t; i < 2048; i += 256) sd[i] = dom[i];
    for (int i = t; i < 8192; i += 256) sr[i] = rec[i];
    __syncthreads();
    if (t < 80) {
        const float* base = (t < 16) ? (sd + t * 128) : (sr + (t - 16) * 128);
        float s = 0.f;
        for (int k = 0; k < 128; ++k) s += base[k] * base[k];
        scale[t] = 1.0f / fmaxf(sqrtf(s), 1e-12f);
    }
    __syncthreads();
    for (int o = t; o < 1024; o += 256) {
        int b = o >> 6, p = o & 63;
        const float* dv = sd + b * 128;
        const float* rv = sr + p * 128;
        float s = 0.f;
        for (int k = 0; k < 128; ++k) s += dv[k] * rv[k];
        float val = s * scale[b] * scale[16 + p];
        dout[b * 64 + p] = val;
        comb[b * 1091 + p] = val;
    }
}

// ===========================================================================
// FUSED gradient + conv1 (2->32, 3x3 SAME) + ReLU + maxpool2 -> h1 NHWC fp16
// Tap-outer / oc-inner with 64 live h2v accumulators: forces register
// residency (the r5 version got rematerialized to 20 VGPRs and re-read LDS
// 240x/thread). LDS reads now 36/thread; weights are uniform scalar loads.
// ===========================================================================
__global__ void __launch_bounds__(256, 4) grad_conv1(const float* __restrict__ img,
                                                     const h2v* __restrict__ w1d,
                                                     const float* __restrict__ c1b,
                                                     _Float16* __restrict__ h1) {
    __shared__ float simg[36 * 37];
    __shared__ _Float16 smag2[35 * 36 * 2];   // [row][p] = (v[p], v[p+1])
    __shared__ _Float16 sori2[35 * 36 * 2];
    const int blk = blockIdx.x;               // b*256 + tile
    const int b = blk >> 8;
    const int tr = blk & 255;
    const int ty0 = (tr >> 4) * 16, tx0 = (tr & 15) * 16;
    const int t = threadIdx.x;
    const float* im = img + (long long)b * 262144;
    const int iy0 = 2 * ty0 - 2, ix0 = 2 * tx0 - 2;

    for (int idx = t; idx < 1296; idx += 256) {
        int iy = idx / 36, ix = idx - iy * 36;
        int gy = min(max(iy0 + iy, 0), 511);
        int gx = min(max(ix0 + ix, 0), 511);
        simg[iy * 37 + ix] = im[gy * 512 + gx];
    }
    __syncthreads();

    for (int idx = t; idx < 1260; idx += 256) {
        int iy = idx / 36, ix = idx - iy * 36;       // grad-local coords
        int gy = 2 * ty0 - 1 + iy, gx = 2 * tx0 - 1 + ix;
        float up = simg[iy * 37 + ix + 1];
        float dn = simg[(iy + 2) * 37 + ix + 1];
        float lf = simg[(iy + 1) * 37 + ix];
        float rt = simg[(iy + 1) * 37 + ix + 2];
        float fy = (gy <= 0 || gy >= 511) ? 1.f : 0.5f;
        float fx = (gx <= 0 || gx >= 511) ? 1.f : 0.5f;
        float gyv = (dn - up) * fy, gxv = (rt - lf) * fx;
        bool inside = ((unsigned)gy < 512u) && ((unsigned)gx < 512u);
        float mag = inside ? sqrtf(gxv * gxv + gyv * gyv) : 0.f;
        float ori = inside ? atan2f(gyv, gxv) : 0.f;
        _Float16 hm = (_Float16)mag, ho = (_Float16)ori;
        if (ix < 35) {
            smag2[(iy * 36 + ix) * 2]     = hm;
            sori2[(iy * 36 + ix) * 2]     = ho;
        }
        if (ix > 0) {
            smag2[(iy * 36 + ix - 1) * 2 + 1] = hm;
            sori2[(iy * 36 + ix - 1) * 2 + 1] = ho;
        }
    }
    __syncthreads();

    const int ly = t >> 4, lx = t & 15;
    h2v acc0[32], acc1[32];
#pragma unroll
    for (int oc = 0; oc < 32; ++oc) {
        _Float16 hb = (_Float16)c1b[oc];
        acc0[oc] = h2v{hb, hb};
        acc1[oc] = h2v{hb, hb};
    }
#pragma unroll
    for (int tap = 0; tap < 9; ++tap) {
        const int ky = tap / 3, kx = tap - ky * 3;
        const int p0 = (2 * ly + ky) * 36 + 2 * lx + kx;
        h2v im0 = *(const h2v*)(smag2 + p0 * 2);
        h2v im1 = *(const h2v*)(smag2 + (p0 + 36) * 2);
        h2v io0 = *(const h2v*)(sori2 + p0 * 2);
        h2v io1 = *(const h2v*)(sori2 + (p0 + 36) * 2);
#pragma unroll
        for (int oc = 0; oc < 32; ++oc) {
            h2v wm = w1d[(tap * 32 + oc) * 2];
            h2v wo = w1d[(tap * 32 + oc) * 2 + 1];
            acc0[oc] += wm * im0;
            acc0[oc] += wo * io0;
            acc1[oc] += wm * im1;
            acc1[oc] += wo * io1;
        }
    }
    union { _Float16 h[32]; floatx4 v[4]; } outp;
#pragma unroll
    for (int oc = 0; oc < 32; ++oc) {
        float m = fmaxf(fmaxf((float)acc0[oc][0], (float)acc0[oc][1]),
                        fmaxf((float)acc1[oc][0], (float)acc1[oc][1]));
        outp.h[oc] = (_Float16)fmaxf(m, 0.f);
    }
    const int py = ty0 + ly, px = tx0 + lx;
    floatx4* dst = (floatx4*)(h1 + (((size_t)b * 65536) + py * 256 + px) * 32);
#pragma unroll
    for (int c = 0; c < 4; ++c) dst[c] = outp.v[c];
}

// ===========================================================================
// conv2 (32->64, 3x3 SAME) + ReLU + 64x64 avg-pool partials — implicit GEMM
// via mfma_f32_16x16x32_f16.
// ===========================================================================
__global__ void __launch_bounds__(256) conv2_mfma(const _Float16* __restrict__ h1,
                                                  const half8* __restrict__ wrep,
                                                  const float* __restrict__ c2b,
                                                  float* __restrict__ sacc) {
    __shared__ _Float16 tile[18 * 34 * 32];     // [row][px][ic] 39,168 B
    __shared__ float lsum[64];
    const int blk = blockIdx.x;                 // b*128 + yt*8 + xt
    const int b  = blk >> 7;
    const int yt = (blk >> 3) & 15;
    const int xt = blk & 7;
    const int y0 = yt * 16, x0 = xt * 32;
    const int t = threadIdx.x;
    if (t < 64) lsum[t] = 0.f;

    for (int c = t; c < 18 * 136; c += 256) {
        int row = c / 136;
        int chunk = c - row * 136;
        int gy = y0 - 1 + row;
        int px = chunk >> 2;
        int gx = x0 - 1 + px;
        floatx4 v = {0.f, 0.f, 0.f, 0.f};
        if ((unsigned)gy < 256u && (unsigned)gx < 256u)
            v = *(const floatx4*)(h1 + (((size_t)(b * 256 + gy)) * 256 + gx) * 32 + (chunk & 3) * 8);
        *(floatx4*)(tile + (row * 34 + px) * 32 + (chunk & 3) * 8) = v;
    }
    __syncthreads();

    const int w = t >> 6, lane = t & 63;
    const int q = lane >> 4, ln15 = lane & 15;
    float bias[4];
#pragma unroll
    for (int nt = 0; nt < 4; ++nt) bias[nt] = c2b[nt * 16 + ln15];
    float partial[4] = {0.f, 0.f, 0.f, 0.f};

#pragma unroll 1
    for (int gr = 0; gr < 2; ++gr) {
        floatx4 acc[4][4];
#pragma unroll
        for (int mt = 0; mt < 4; ++mt)
#pragma unroll
            for (int nt = 0; nt < 4; ++nt)
                acc[mt][nt] = floatx4{bias[nt], bias[nt], bias[nt], bias[nt]};
#pragma unroll 1
        for (int tap = 0; tap < 9; ++tap) {
            const int ky = tap / 3, kx = tap - ky * 3;
            half8 Bf[4];
#pragma unroll
            for (int nt = 0; nt < 4; ++nt) Bf[nt] = wrep[(tap * 4 + nt) * 64 + lane];
#pragma unroll
            for (int mt = 0; mt < 4; ++mt) {
                int r = w * 4 + gr * 2 + (mt >> 1);
                int xh = mt & 1;
                half8 Af = *(const half8*)(tile + ((r + ky) * 34 + xh * 16 + ln15 + kx) * 32 + q * 8);
#pragma unroll
                for (int nt = 0; nt < 4; ++nt)
                    acc[mt][nt] = __builtin_amdgcn_mfma_f32_16x16x32_f16(Af, Bf[nt], acc[mt][nt], 0, 0, 0);
            }
        }
#pragma unroll
        for (int mt = 0; mt < 4; ++mt)
#pragma unroll
            for (int nt = 0; nt < 4; ++nt)
#pragma unroll
                for (int rg = 0; rg < 4; ++rg)
                    partial[nt] += fmaxf(acc[mt][nt][rg], 0.f);
    }

#pragma unroll
    for (int nt = 0; nt < 4; ++nt) {
        float v = partial[nt];
        v += __shfl_xor(v, 16);
        v += __shfl_xor(v, 32);
        if (lane < 16) atomicAdd(&lsum[nt * 16 + ln15], v);
    }
    __syncthreads();
    const int cell = (yt >> 2) * 4 + (xt >> 1);
    if (t < 64) atomicAdd(&sacc[(((b << 6) + t) << 4) + cell], lsum[t]);
}

// ===========================================================================
// combined finalize: blocks 0..63 spatial, block 64 phase
// ===========================================================================
__global__ void __launch_bounds__(256) finalize_kernel(const float* __restrict__ sacc,
                                                       const float* __restrict__ psum,
                                                       const float* __restrict__ psumsq,
                                                       const unsigned* __restrict__ phist,
                                                       float* __restrict__ comb,
                                                       float* __restrict__ dout) {
    if (blockIdx.x < 64) {
        int idx = blockIdx.x * 256 + threadIdx.x;     // 16384
        int b = idx >> 10, j = idx & 1023;
        float v = sacc[idx] * (1.0f / 4096.0f);
        dout[1024 + idx] = v;
        comb[b * 1091 + 64 + j] = v;
    } else {
        int t = threadIdx.x;
        if (t < 16) {
            const float N = 262144.f;
            float s = psum[t];
            float mean = s / N;
            float var = (psumsq[t] - s * s / N) / (N - 1.f);
            float sd = sqrtf(fmaxf(var, 0.f));
            float ent = 0.f;
            for (int i = 0; i < 64; ++i) {
                float p = (float)phist[t * 64 + i] / N;
                ent -= p * logf(p + 1e-10f);
            }
            dout[17408 + t * 3 + 0] = mean;
            dout[17408 + t * 3 + 1] = sd;
            dout[17408 + t * 3 + 2] = ent;
            float* cb = comb + t * 1091 + 1088;
            cb[0] = mean; cb[1] = sd; cb[2] = ent;
        }
    }
}

// ===========================================================================
// fc1: wave per (b,o), coalesced weight-row sweep + shuffle reduce
// ===========================================================================
__global__ void __launch_bounds__(256) fc1_kernel(const float* __restrict__ comb,
                                                  const float* __restrict__ W1,
                                                  const float* __restrict__ B1,
                                                  float* __restrict__ out1) {
    const int wid = blockIdx.x * 4 + (threadIdx.x >> 6);  // 0..8191
    const int lane = threadIdx.x & 63;
    const int b = wid >> 9, o = wid & 511;
    const float* w = W1 + (size_t)o * 1091;
    const float* c = comb + b * 1091;
    float acc = 0.f;
#pragma unroll 4
    for (int i = 0; i < 17; ++i) {
        int k = i * 64 + lane;
        acc += w[k] * c[k];                     // 17*64 = 1088
    }
    if (lane < 3) acc += w[1088 + lane] * c[1088 + lane];
#pragma unroll
    for (int off = 32; off > 0; off >>= 1) acc += __shfl_down(acc, off);
    if (lane == 0) out1[b * 512 + o] = fmaxf(acc + B1[o], 0.f);
}

// ===========================================================================
// fc2: wave per (b,o)
// ===========================================================================
__global__ void __launch_bounds__(256) fc2_kernel(const float* __restrict__ out1,
                                                  const float* __restrict__ W2,
                                                  const float* __restrict__ B2,
                                                  float* __restrict__ z) {
    const int wid = blockIdx.x * 4 + (threadIdx.x >> 6);  // 0..2047
    const int lane = threadIdx.x & 63;
    const int b = wid >> 7, o = wid & 127;
    const float* w = W2 + (size_t)o * 512;
    const float* c = out1 + b * 512;
    float acc = 0.f;
#pragma unroll
    for (int i = 0; i < 8; ++i) {
        int k = i * 64 + lane;
        acc += w[k] * c[k];
    }
#pragma unroll
    for (int off = 32; off > 0; off >>= 1) acc += __shfl_down(acc, off);
    if (lane == 0) z[b * 128 + o] = acc + B2[o];
}

// ===========================================================================
// layernorm over z[16,128] -> holo
// ===========================================================================
__global__ void __launch_bounds__(128) ln_kernel(const float* __restrict__ z,
                                                 const float* __restrict__ g,
                                                 const float* __restrict__ beta,
                                                 float* __restrict__ dout) {
    __shared__ float red[4];
    const int b = blockIdx.x, t = threadIdx.x;
    float acc = z[b * 128 + t];
    float s = acc;
    for (int off = 32; off > 0; off >>= 1) s += __shfl_down(s, off);
    if ((t & 63) == 0) red[t >> 6] = s;
    __syncthreads();
    float mu = (red[0] + red[1]) * (1.0f / 128.0f);
    float d = acc - mu;
    float q = d * d;
    for (int off = 32; off > 0; off >>= 1) q += __shfl_down(q, off);
    if ((t & 63) == 0) red[2 + (t >> 6)] = q;
    __syncthreads();
    float var = (red[2] + red[3]) * (1.0f / 128.0f);
    dout[17456 + b * 128 + t] = d / sqrtf(var + 1e-5f) * g[t] + beta[t];
}

// ===========================================================================
// launcher
// ===========================================================================
extern "C" void kernel_launch(void* const* d_in, const int* in_sizes, int n_in,
                              void* d_out, int out_size, void* d_ws, size_t ws_size,
                              hipStream_t stream) {
    const float* img = (const float*)d_in[0];
    const float* rec = (const float*)d_in[1];
    const float* w1  = (const float*)d_in[2];
    const float* c1b = (const float*)d_in[3];
    const float* w2  = (const float*)d_in[4];
    const float* c2b = (const float*)d_in[5];
    const float* fw1 = (const float*)d_in[6];
    const float* fb1 = (const float*)d_in[7];
    const float* fw2 = (const float*)d_in[8];
    const float* fb2 = (const float*)d_in[9];
    const float* lng = (const float*)d_in[10];
    const float* lnb = (const float*)d_in[11];
    float* out = (float*)d_out;

    float* ws = (float*)d_ws;
    float2* rowfft = (float2*)ws;                 // region0
    float* magT    = ws + OFF_BIG;                // region1
    _Float16* h1   = (_Float16*)(ws + OFF_BIG);   // alias (magT dead after collect) NHWC
    float* small_  = ws + OFF_SMALL;
    float* sacc    = small_;                      // 16384
    float* psum    = small_ + 16384;              // 16
    float* psumsq  = small_ + 16400;              // 16
    unsigned* phist = (unsigned*)(small_ + 16416);// 1024
    unsigned* mhist = (unsigned*)(small_ + 17440);// NBIN*16 = 32768 (region sized 65536)
    unsigned* ccnt  = (unsigned*)(small_ + 82976);// 16    (zeroed range ends at 82992)
    int* selbin    = (int*)(small_ + 82992);      // 16
    float* dom     = small_ + 83008;              // 2048
    float* comb    = small_ + 85056;              // 17456
    float* out1    = small_ + 102512;             // 8192
    _Float16* wrep = (_Float16*)(small_ + 110704);// 18432 f16 = 9216 dwords
    float2* twg    = (float2*)(small_ + 119920);  // 512 float2 = 1024 dwords
    float* cand    = small_ + 120944;             // 16*4096 = 65536 dwords
    float* zbuf    = cand;                        // alias (cand dead after sort)
    _Float16* w1d  = (_Float16*)(small_ + 186480);// 9*32*4 f16 = 576 dwords

    init_kernel<<<325, 256, 0, stream>>>(sacc, twg, w2, w1, wrep, w1d);
    fft_rows<<<8192, 256, 0, stream>>>(img, twg, rowfft);
    fft_cols<<<1024, 256, 0, stream>>>(rowfft, twg, magT, psum, psumsq, phist, mhist);
    thresh_kernel<<<16, 256, 0, stream>>>(mhist, selbin);
    collect_kernel<<<256, 256, 0, stream>>>(magT, selbin, cand, ccnt);
    sort_kernel<<<16, 1024, 0, stream>>>(cand, ccnt, dom);
    sims_kernel<<<1, 256, 0, stream>>>(dom, rec, comb, out);
    grad_conv1<<<4096, 256, 0, stream>>>(img, (const h2v*)w1d, c1b, h1);
    conv2_mfma<<<2048, 256, 0, stream>>>(h1, (const half8*)wrep, c2b, sacc);
    finalize_kernel<<<65, 256, 0, stream>>>(sacc, psum, psumsq, phist, comb, out);
    fc1_kernel<<<2048, 256, 0, stream>>>(comb, fw1, fb1, out1);
    fc2_kernel<<<512, 256, 0, stream>>>(out1, fw2, fb2, zbuf);
    ln_kernel<<<16, 128, 0, stream>>>(zbuf, lng, lnb, out);
}

// Round 7
// 333.019 us; speedup vs baseline: 5.7300x; 1.0733x over previous
//
#include <hip/hip_runtime.h>
#include <hip/hip_fp16.h>
#include <math.h>

// ---------------------------------------------------------------------------
// HolographicPatternExtractor  (B=16, C=1, H=W=512)
//  outputs (flat f32): sims[16,64] | spatial[16,1024] | phase_feats[16,3] | holo[16,128]
// ---------------------------------------------------------------------------

#define PI_F 3.14159274f          // float(np.pi)
#define TWO_PI_F 6.28318548f

typedef _Float16 half8 __attribute__((ext_vector_type(8)));
typedef float floatx4 __attribute__((ext_vector_type(4)));

// ---- workspace layout (dword offsets) ----
#define OFF_BIG   8388608
#define OFF_SMALL 25165824
#define NBIN 2048                 // magnitude histogram bins (bits>>20)

// ===========================================================================
// combined init: zero accumulators + twiddle table + weight repacks
// ===========================================================================
__global__ void __launch_bounds__(256) init_kernel(float* __restrict__ zp,
                                                   float2* __restrict__ tw,
                                                   const float* __restrict__ w2,
                                                   const float* __restrict__ w1,
                                                   _Float16* __restrict__ wrep,
                                                   _Float16* __restrict__ w1r) {
    int idx = blockIdx.x * 256 + threadIdx.x;
    if (idx < 82992) zp[idx] = 0.0f;
    if (idx < 512) {
        if (idx == 0) tw[0] = make_float2(1.f, 0.f);
        else {
            int h = 31 - __clz(idx);
            int H = 1 << h;
            float sn, cs;
            sincosf(-PI_F * (float)(idx - H) / (float)H, &sn, &cs);
            tw[idx] = make_float2(cs, sn);
        }
    }
    if (idx < 18432) {            // conv2 MFMA B-fragment
        int j = idx & 7;
        int lane = (idx >> 3) & 63;
        int nt = (idx >> 9) & 3;
        int tap = idx >> 11;
        int oc = nt * 16 + (lane & 15);
        int ic = (lane >> 4) * 8 + j;
        wrep[idx] = (_Float16)w2[(oc * 32 + ic) * 9 + tap];
    }
    if (idx < 1024) {             // conv1 MFMA B-fragment: [nt][lane][j]
        int j = idx & 7;
        int lane = (idx >> 3) & 63;
        int nt = idx >> 9;
        int oc = nt * 16 + (lane & 15);
        int k = (lane >> 4) * 8 + j;      // k = 2*tap + ch, pad >=18 with 0
        _Float16 v = (_Float16)0.f;
        if (k < 18) {
            int tap = k >> 1, ch = k & 1;
            v = (_Float16)w1[oc * 18 + ch * 9 + tap];
        }
        w1r[idx] = v;
    }
}

// ===========================================================================
// FFT row pass (DIF, natural input, bit-reversed output — consumers are
// order-invariant). One 512-pt FFT per block.
// ===========================================================================
__global__ void __launch_bounds__(256) fft_rows(const float* __restrict__ img,
                                                const float2* __restrict__ twg,
                                                float2* __restrict__ rowfft) {
    __shared__ float2 s[512];
    __shared__ float2 tw[512];
    const int t = threadIdx.x;
    const int row = blockIdx.x;                 // b*512 + y
    const float* x = img + (long long)row * 512;

    for (int i = t; i < 512; i += 256) tw[i] = twg[i];
    for (int i = t; i < 512; i += 256) s[i] = make_float2(x[i], 0.f);
    __syncthreads();
#pragma unroll
    for (int st = 9; st >= 1; --st) {
        const int half = 1 << (st - 1);
        const int pos = t & (half - 1);
        const int grp = t >> (st - 1);
        const int i1 = (grp << st) + pos;
        const int i2 = i1 + half;
        float2 w = tw[half + pos];
        float2 a = s[i1], b = s[i2];
        float dx = a.x - b.x, dy = a.y - b.y;
        s[i1] = make_float2(a.x + b.x, a.y + b.y);
        s[i2] = make_float2(dx * w.x - dy * w.y, dx * w.y + dy * w.x);
        __syncthreads();
    }
    for (int i = t; i < 512; i += 256) rowfft[(long long)row * 512 + i] = s[i];
}

// ===========================================================================
// FFT column pass (DIF): 8 columns/block; fused magnitude (transposed store)
// + phase stats + magnitude histogram (2048 bins, for top-k threshold)
// ===========================================================================
__global__ void __launch_bounds__(256) fft_cols(const float2* __restrict__ rowfft,
                                                const float2* __restrict__ twg,
                                                float* __restrict__ magT,
                                                float* __restrict__ psum,
                                                float* __restrict__ psumsq,
                                                unsigned* __restrict__ phist,
                                                unsigned* __restrict__ mhist) {
    __shared__ float2 s[8 * 512];               // column c contiguous at c*512
    __shared__ float2 tw[512];
    __shared__ unsigned ph[64];
    __shared__ unsigned mh[NBIN];
    __shared__ float red[8];
    const int t = threadIdx.x;
    const int b = blockIdx.x >> 6;
    const int x0 = (blockIdx.x & 63) * 8;

    for (int i = t; i < 512; i += 256) tw[i] = twg[i];
    if (t < 64) ph[t] = 0u;
    for (int i = t; i < NBIN; i += 256) mh[i] = 0u;
    for (int idx = t; idx < 8 * 512; idx += 256) {
        int y = idx >> 3;
        int c = idx & 7;
        s[c * 512 + y] = rowfft[((long long)(b * 512 + y)) * 512 + x0 + c];
    }
    __syncthreads();

    const int c = t >> 5;                       // 8 columns x 32 threads
    const int j0 = t & 31;
    float2* sc = s + c * 512;
#pragma unroll
    for (int st = 9; st >= 1; --st) {
        const int half = 1 << (st - 1);
#pragma unroll
        for (int k = 0; k < 8; ++k) {
            int j = j0 + (k << 5);
            int pos = j & (half - 1);
            int grp = j >> (st - 1);
            int i1 = (grp << st) + pos;
            int i2 = i1 + half;
            float2 w = tw[half + pos];
            float2 a = sc[i1], bb = sc[i2];
            float dx = a.x - bb.x, dy = a.y - bb.y;
            sc[i1] = make_float2(a.x + bb.x, a.y + bb.y);
            sc[i2] = make_float2(dx * w.x - dy * w.y, dx * w.y + dy * w.x);
        }
        __syncthreads();
    }

    float lsum = 0.f, lsq = 0.f;
    for (int idx = t; idx < 8 * 512; idx += 256) {
        int cc = idx >> 9;
        int y = idx & 511;
        float2 v = s[cc * 512 + y];
        float mag = sqrtf(v.x * v.x + v.y * v.y);
        magT[((long long)(b * 512 + x0 + cc)) * 512 + y] = mag;
        unsigned mb = min(__float_as_uint(mag) >> 20, (unsigned)(NBIN - 1));
        atomicAdd(&mh[mb], 1u);
        float phv = atan2f(v.y, v.x);
        lsum += phv;
        lsq += phv * phv;
        int bin = (int)floorf((phv + PI_F) / TWO_PI_F * 64.0f);
        bin = min(max(bin, 0), 63);
        atomicAdd(&ph[bin], 1u);
    }
    for (int off = 32; off > 0; off >>= 1) {
        lsum += __shfl_down(lsum, off);
        lsq  += __shfl_down(lsq, off);
    }
    if ((t & 63) == 0) { red[t >> 6] = lsum; red[4 + (t >> 6)] = lsq; }
    __syncthreads();
    if (t == 0) {
        atomicAdd(psum + b,   red[0] + red[1] + red[2] + red[3]);
        atomicAdd(psumsq + b, red[4] + red[5] + red[6] + red[7]);
    }
    if (t < 64 && ph[t]) atomicAdd(&phist[b * 64 + t], ph[t]);
    for (int i = t; i < NBIN; i += 256)
        if (mh[i]) atomicAdd(&mhist[b * NBIN + i], mh[i]);
}

// ===========================================================================
// top-k: threshold bin from histogram suffix-count
// ===========================================================================
__global__ void __launch_bounds__(256) thresh_kernel(const unsigned* __restrict__ mhist,
                                                     int* __restrict__ selbin) {
    __shared__ unsigned csum[256];
    const int b = blockIdx.x, t = threadIdx.x;
    unsigned s = 0;
    for (int i = 0; i < NBIN / 256; ++i) s += mhist[b * NBIN + t * (NBIN / 256) + i];
    csum[t] = s;
    __syncthreads();
    if (t == 0) {
        unsigned acc = 0; int chunk = 0;
        for (int i = 255; i >= 0; --i) {
            acc += csum[i];
            if (acc >= 128u) { chunk = i; break; }
        }
        unsigned acc2 = acc - csum[chunk];      // count strictly above chunk
        int tb = chunk * (NBIN / 256);
        for (int i = chunk * (NBIN / 256) + (NBIN / 256) - 1; i >= chunk * (NBIN / 256); --i) {
            acc2 += mhist[b * NBIN + i];
            if (acc2 >= 128u) { tb = i; break; }
        }
        selbin[b] = tb;
    }
}

// ===========================================================================
// top-k: parallel candidate collection (256 blocks)
// ===========================================================================
#define TK_CAP 4096
__global__ void __launch_bounds__(256) collect_kernel(const float* __restrict__ magT,
                                                      const int* __restrict__ selbin,
                                                      float* __restrict__ cand,
                                                      unsigned* __restrict__ ccnt) {
    const int blk = blockIdx.x;
    const int b = blk >> 4, chunk = blk & 15;
    const unsigned tb = (unsigned)selbin[b];
    const floatx4* m = (const floatx4*)(magT + (long long)b * 262144 + chunk * 16384);
    float* cb = cand + b * TK_CAP;
    for (int i = threadIdx.x; i < 4096; i += 256) {
        floatx4 v = m[i];
#pragma unroll
        for (int k = 0; k < 4; ++k) {
            float x = v[k];
            unsigned bin = min(__float_as_uint(x) >> 20, (unsigned)(NBIN - 1));
            if (bin >= tb) {
                unsigned p = atomicAdd(&ccnt[b], 1u);
                if (p < TK_CAP) cb[p] = x;
            }
        }
    }
}

// ===========================================================================
// top-k: bitonic sort descending of candidates -> dom[b][128]
// ===========================================================================
__global__ void __launch_bounds__(1024) sort_kernel(const float* __restrict__ cand,
                                                    const unsigned* __restrict__ ccnt,
                                                    float* __restrict__ dom) {
    __shared__ float c[TK_CAP];
    const int b = blockIdx.x, t = threadIdx.x;
    const unsigned n = min(ccnt[b], (unsigned)TK_CAP);
    int P = 256;
    while (P < (int)n) P <<= 1;                 // 256..4096
    for (int i = t; i < P; i += 1024) c[i] = (i < (int)n) ? cand[b * TK_CAP + i] : -1.0f;
    __syncthreads();
    for (int k = 2; k <= P; k <<= 1) {
        for (int j = k >> 1; j > 0; j >>= 1) {
            for (int i = t; i < P; i += 1024) {
                int ixj = i ^ j;
                if (ixj > i) {
                    float a = c[i], d = c[ixj];
                    bool up = ((i & k) == 0);
                    if (up ? (a < d) : (a > d)) { c[i] = d; c[ixj] = a; }
                }
            }
            __syncthreads();
        }
    }
    if (t < 128) dom[b * 128 + t] = c[t];
}

// ===========================================================================
// sims = normalize(dom) @ normalize(receptors)^T
// ===========================================================================
__global__ void __launch_bounds__(256) sims_kernel(const float* __restrict__ dom,
                                                   const float* __restrict__ rec,
                                                   float* __restrict__ comb,
                                                   float* __restrict__ dout) {
    __shared__ float sd[16 * 128];
    __shared__ float sr[64 * 128];
    __shared__ float scale[80];
    const int t = threadIdx.x;
    for (int i = t; i < 2048; i += 256) sd[i] = dom[i];
    for (int i = t; i < 8192; i += 256) sr[i] = rec[i];
    __syncthreads();
    if (t < 80) {
        const float* base = (t < 16) ? (sd + t * 128) : (sr + (t - 16) * 128);
        float s = 0.f;
        for (int k = 0; k < 128; ++k) s += base[k] * base[k];
        scale[t] = 1.0f / fmaxf(sqrtf(s), 1e-12f);
    }
    __syncthreads();
    for (int o = t; o < 1024; o += 256) {
        int b = o >> 6, p = o & 63;
        const float* dv = sd + b * 128;
        const float* rv = sr + p * 128;
        float s = 0.f;
        for (int k = 0; k < 128; ++k) s += dv[k] * rv[k];
        float val = s * scale[b] * scale[16 + p];
        dout[b * 64 + p] = val;
        comb[b * 1091 + p] = val;
    }
}

// ===========================================================================
// FUSED gradient + conv1 + ReLU + maxpool2 -> h1 NHWC fp16, via MFMA
// implicit GEMM (M = pre-pool pixels ordered pooled*4+sub, N=32 oc, K=18->32).
// Gradient pairs (mag,ori) live in LDS as dwords; A-frag = 4 quad-selected
// ds_read_b32 (zero-pair fallback covers K padding). C-layout row =
// (lane>>4)*4+reg puts the 4 maxpool sub-pixels in one lane's 4 acc regs.
// ===========================================================================
__global__ void __launch_bounds__(256) grad_conv1_mfma(const float* __restrict__ img,
                                                       const half8* __restrict__ w1r,
                                                       const float* __restrict__ c1b,
                                                       _Float16* __restrict__ h1) {
    __shared__ float simg[36 * 37];
    __shared__ _Float16 sgrad[(34 * 36 + 1) * 2];   // [(y+1)*36+(x+1)] -> (mag,ori); +1 zero pair
    const int blk = blockIdx.x;               // b*256 + tile
    const int b = blk >> 8;
    const int tr = blk & 255;                 // 16x16 tiles of 32 pre-pool px
    const int TY = (tr >> 4) * 32, TX = (tr & 15) * 32;
    const int t = threadIdx.x;
    const float* im = img + (long long)b * 262144;

    // ---- stage img 36x36: rows TY-2..TY+33 (clamped) ----------------------
    for (int idx = t; idx < 1296; idx += 256) {
        int iy = idx / 36, ix = idx - iy * 36;
        int gy = min(max(TY - 2 + iy, 0), 511);
        int gx = min(max(TX - 2 + ix, 0), 511);
        simg[iy * 37 + ix] = im[gy * 512 + gx];
    }
    if (t == 0) { sgrad[2448] = (_Float16)0.f; sgrad[2449] = (_Float16)0.f; }
    __syncthreads();

    // ---- gradient 34x34 (px -1..32 rel. tile), zero outside image ---------
    for (int idx = t; idx < 1156; idx += 256) {
        int ly = idx / 34, lx = idx - ly * 34;       // 0..33
        int gy = TY - 1 + ly, gx = TX - 1 + lx;
        float up = simg[ly * 37 + lx + 1];
        float dn = simg[(ly + 2) * 37 + lx + 1];
        float lf = simg[(ly + 1) * 37 + lx];
        float rt = simg[(ly + 1) * 37 + lx + 2];
        float fy = (gy <= 0 || gy >= 511) ? 1.f : 0.5f;
        float fx = (gx <= 0 || gx >= 511) ? 1.f : 0.5f;
        float gyv = (dn - up) * fy, gxv = (rt - lf) * fx;
        bool inside = ((unsigned)gy < 512u) && ((unsigned)gx < 512u);
        float mag = inside ? sqrtf(gxv * gxv + gyv * gyv) : 0.f;
        float ori = inside ? atan2f(gyv, gxv) : 0.f;
        int p = (ly * 36 + lx) * 2;
        sgrad[p] = (_Float16)mag;
        sgrad[p + 1] = (_Float16)ori;
    }
    __syncthreads();

    const int w = t >> 6, lane = t & 63;
    const int q = lane >> 4, m = lane & 15;
    const int oc0 = m, oc1 = 16 + m;          // C cols this lane owns
    const float bias0 = c1b[oc0], bias1 = c1b[oc1];
    half8 Bf0 = w1r[lane], Bf1 = w1r[64 + lane];
    const unsigned* gp = (const unsigned*)sgrad;   // (mag,ori) dword pairs
    const int ZP = 1224;                      // zero pair index

    // A-row pixel for this lane (within each m-tile): sub = m&3, dqx = m>>2
    const int sy = (m >> 1) & 1, sx = m & 1, dqx = m >> 2;

#pragma unroll 4
    for (int i = 0; i < 16; ++i) {
        const int mt = w * 16 + i;            // 0..63
        const int qy = mt >> 2, qxg = mt & 3; // pooled row / qx group
        const int py = 2 * qy + sy;           // pre-pool tile-local
        const int px = 2 * (qxg * 4 + dqx) + sx;
        const int base = py * 36 + px;        // tap(0,0) pair index

        int o0 = (q == 0) ? base      : (q == 1) ? base + 37 : (q == 2) ? base + 74 : ZP;
        int o1 = (q == 0) ? base + 1  : (q == 1) ? base + 38 : ZP;
        int o2 = (q == 0) ? base + 2  : (q == 1) ? base + 72 : ZP;
        int o3 = (q == 0) ? base + 36 : (q == 1) ? base + 73 : ZP;

        union { unsigned u[4]; half8 h; } Af;
        Af.u[0] = gp[o0]; Af.u[1] = gp[o1]; Af.u[2] = gp[o2]; Af.u[3] = gp[o3];

        floatx4 acc0 = {bias0, bias0, bias0, bias0};
        floatx4 acc1 = {bias1, bias1, bias1, bias1};
        acc0 = __builtin_amdgcn_mfma_f32_16x16x32_f16(Af.h, Bf0, acc0, 0, 0, 0);
        acc1 = __builtin_amdgcn_mfma_f32_16x16x32_f16(Af.h, Bf1, acc1, 0, 0, 0);

        // maxpool over the 4 sub-pixels (this lane's 4 acc regs) + relu
        float v0 = fmaxf(fmaxf(acc0[0], acc0[1]), fmaxf(acc0[2], acc0[3]));
        float v1 = fmaxf(fmaxf(acc1[0], acc1[1]), fmaxf(acc1[2], acc1[3]));
        v0 = fmaxf(v0, 0.f);
        v1 = fmaxf(v1, 0.f);

        const int PY = (TY >> 1) + qy;
        const int PX = (TX >> 1) + qxg * 4 + q;
        _Float16* dst = h1 + (((size_t)(b * 256 + PY)) * 256 + PX) * 32;
        dst[oc0] = (_Float16)v0;
        dst[oc1] = (_Float16)v1;
    }
}

// ===========================================================================
// conv2 (32->64, 3x3 SAME) + ReLU + 64x64 avg-pool partials — implicit GEMM
// via mfma_f32_16x16x32_f16.
// ===========================================================================
__global__ void __launch_bounds__(256) conv2_mfma(const _Float16* __restrict__ h1,
                                                  const half8* __restrict__ wrep,
                                                  const float* __restrict__ c2b,
                                                  float* __restrict__ sacc) {
    __shared__ _Float16 tile[18 * 34 * 32];     // [row][px][ic] 39,168 B
    __shared__ float lsum[64];
    const int blk = blockIdx.x;                 // b*128 + yt*8 + xt
    const int b  = blk >> 7;
    const int yt = (blk >> 3) & 15;
    const int xt = blk & 7;
    const int y0 = yt * 16, x0 = xt * 32;
    const int t = threadIdx.x;
    if (t < 64) lsum[t] = 0.f;

    for (int c = t; c < 18 * 136; c += 256) {
        int row = c / 136;
        int chunk = c - row * 136;
        int gy = y0 - 1 + row;
        int px = chunk >> 2;
        int gx = x0 - 1 + px;
        floatx4 v = {0.f, 0.f, 0.f, 0.f};
        if ((unsigned)gy < 256u && (unsigned)gx < 256u)
            v = *(const floatx4*)(h1 + (((size_t)(b * 256 + gy)) * 256 + gx) * 32 + (chunk & 3) * 8);
        *(floatx4*)(tile + (row * 34 + px) * 32 + (chunk & 3) * 8) = v;
    }
    __syncthreads();

    const int w = t >> 6, lane = t & 63;
    const int q = lane >> 4, ln15 = lane & 15;
    float bias[4];
#pragma unroll
    for (int nt = 0; nt < 4; ++nt) bias[nt] = c2b[nt * 16 + ln15];
    float partial[4] = {0.f, 0.f, 0.f, 0.f};

#pragma unroll 1
    for (int gr = 0; gr < 2; ++gr) {
        floatx4 acc[4][4];
#pragma unroll
        for (int mt = 0; mt < 4; ++mt)
#pragma unroll
            for (int nt = 0; nt < 4; ++nt)
                acc[mt][nt] = floatx4{bias[nt], bias[nt], bias[nt], bias[nt]};
#pragma unroll 1
        for (int tap = 0; tap < 9; ++tap) {
            const int ky = tap / 3, kx = tap - ky * 3;
            half8 Bf[4];
#pragma unroll
            for (int nt = 0; nt < 4; ++nt) Bf[nt] = wrep[(tap * 4 + nt) * 64 + lane];
#pragma unroll
            for (int mt = 0; mt < 4; ++mt) {
                int r = w * 4 + gr * 2 + (mt >> 1);
                int xh = mt & 1;
                half8 Af = *(const half8*)(tile + ((r + ky) * 34 + xh * 16 + ln15 + kx) * 32 + q * 8);
#pragma unroll
                for (int nt = 0; nt < 4; ++nt)
                    acc[mt][nt] = __builtin_amdgcn_mfma_f32_16x16x32_f16(Af, Bf[nt], acc[mt][nt], 0, 0, 0);
            }
        }
#pragma unroll
        for (int mt = 0; mt < 4; ++mt)
#pragma unroll
            for (int nt = 0; nt < 4; ++nt)
#pragma unroll
                for (int rg = 0; rg < 4; ++rg)
                    partial[nt] += fmaxf(acc[mt][nt][rg], 0.f);
    }

#pragma unroll
    for (int nt = 0; nt < 4; ++nt) {
        float v = partial[nt];
        v += __shfl_xor(v, 16);
        v += __shfl_xor(v, 32);
        if (lane < 16) atomicAdd(&lsum[nt * 16 + ln15], v);
    }
    __syncthreads();
    const int cell = (yt >> 2) * 4 + (xt >> 1);
    if (t < 64) atomicAdd(&sacc[(((b << 6) + t) << 4) + cell], lsum[t]);
}

// ===========================================================================
// combined finalize: blocks 0..63 spatial, block 64 phase
// ===========================================================================
__global__ void __launch_bounds__(256) finalize_kernel(const float* __restrict__ sacc,
                                                       const float* __restrict__ psum,
                                                       const float* __restrict__ psumsq,
                                                       const unsigned* __restrict__ phist,
                                                       float* __restrict__ comb,
                                                       float* __restrict__ dout) {
    if (blockIdx.x < 64) {
        int idx = blockIdx.x * 256 + threadIdx.x;     // 16384
        int b = idx >> 10, j = idx & 1023;
        float v = sacc[idx] * (1.0f / 4096.0f);
        dout[1024 + idx] = v;
        comb[b * 1091 + 64 + j] = v;
    } else {
        int t = threadIdx.x;
        if (t < 16) {
            const float N = 262144.f;
            float s = psum[t];
            float mean = s / N;
            float var = (psumsq[t] - s * s / N) / (N - 1.f);
            float sd = sqrtf(fmaxf(var, 0.f));
            float ent = 0.f;
            for (int i = 0; i < 64; ++i) {
                float p = (float)phist[t * 64 + i] / N;
                ent -= p * logf(p + 1e-10f);
            }
            dout[17408 + t * 3 + 0] = mean;
            dout[17408 + t * 3 + 1] = sd;
            dout[17408 + t * 3 + 2] = ent;
            float* cb = comb + t * 1091 + 1088;
            cb[0] = mean; cb[1] = sd; cb[2] = ent;
        }
    }
}

// ===========================================================================
// fc1: wave per (b,o), coalesced weight-row sweep + shuffle reduce
// ===========================================================================
__global__ void __launch_bounds__(256) fc1_kernel(const float* __restrict__ comb,
                                                  const float* __restrict__ W1,
                                                  const float* __restrict__ B1,
                                                  float* __restrict__ out1) {
    const int wid = blockIdx.x * 4 + (threadIdx.x >> 6);  // 0..8191
    const int lane = threadIdx.x & 63;
    const int b = wid >> 9, o = wid & 511;
    const float* w = W1 + (size_t)o * 1091;
    const float* c = comb + b * 1091;
    float acc = 0.f;
#pragma unroll 4
    for (int i = 0; i < 17; ++i) {
        int k = i * 64 + lane;
        acc += w[k] * c[k];                     // 17*64 = 1088
    }
    if (lane < 3) acc += w[1088 + lane] * c[1088 + lane];
#pragma unroll
    for (int off = 32; off > 0; off >>= 1) acc += __shfl_down(acc, off);
    if (lane == 0) out1[b * 512 + o] = fmaxf(acc + B1[o], 0.f);
}

// ===========================================================================
// fc2: wave per (b,o)
// ===========================================================================
__global__ void __launch_bounds__(256) fc2_kernel(const float* __restrict__ out1,
                                                  const float* __restrict__ W2,
                                                  const float* __restrict__ B2,
                                                  float* __restrict__ z) {
    const int wid = blockIdx.x * 4 + (threadIdx.x >> 6);  // 0..2047
    const int lane = threadIdx.x & 63;
    const int b = wid >> 7, o = wid & 127;
    const float* w = W2 + (size_t)o * 512;
    const float* c = out1 + b * 512;
    float acc = 0.f;
#pragma unroll
    for (int i = 0; i < 8; ++i) {
        int k = i * 64 + lane;
        acc += w[k] * c[k];
    }
#pragma unroll
    for (int off = 32; off > 0; off >>= 1) acc += __shfl_down(acc, off);
    if (lane == 0) z[b * 128 + o] = acc + B2[o];
}

// ===========================================================================
// layernorm over z[16,128] -> holo
// ===========================================================================
__global__ void __launch_bounds__(128) ln_kernel(const float* __restrict__ z,
                                                 const float* __restrict__ g,
                                                 const float* __restrict__ beta,
                                                 float* __restrict__ dout) {
    __shared__ float red[4];
    const int b = blockIdx.x, t = threadIdx.x;
    float acc = z[b * 128 + t];
    float s = acc;
    for (int off = 32; off > 0; off >>= 1) s += __shfl_down(s, off);
    if ((t & 63) == 0) red[t >> 6] = s;
    __syncthreads();
    float mu = (red[0] + red[1]) * (1.0f / 128.0f);
    float d = acc - mu;
    float q = d * d;
    for (int off = 32; off > 0; off >>= 1) q += __shfl_down(q, off);
    if ((t & 63) == 0) red[2 + (t >> 6)] = q;
    __syncthreads();
    float var = (red[2] + red[3]) * (1.0f / 128.0f);
    dout[17456 + b * 128 + t] = d / sqrtf(var + 1e-5f) * g[t] + beta[t];
}

// ===========================================================================
// launcher
// ===========================================================================
extern "C" void kernel_launch(void* const* d_in, const int* in_sizes, int n_in,
                              void* d_out, int out_size, void* d_ws, size_t ws_size,
                              hipStream_t stream) {
    const float* img = (const float*)d_in[0];
    const float* rec = (const float*)d_in[1];
    const float* w1  = (const float*)d_in[2];
    const float* c1b = (const float*)d_in[3];
    const float* w2  = (const float*)d_in[4];
    const float* c2b = (const float*)d_in[5];
    const float* fw1 = (const float*)d_in[6];
    const float* fb1 = (const float*)d_in[7];
    const float* fw2 = (const float*)d_in[8];
    const float* fb2 = (const float*)d_in[9];
    const float* lng = (const float*)d_in[10];
    const float* lnb = (const float*)d_in[11];
    float* out = (float*)d_out;

    float* ws = (float*)d_ws;
    float2* rowfft = (float2*)ws;                 // region0
    float* magT    = ws + OFF_BIG;                // region1
    _Float16* h1   = (_Float16*)(ws + OFF_BIG);   // alias (magT dead after collect) NHWC
    float* small_  = ws + OFF_SMALL;
    float* sacc    = small_;                      // 16384
    float* psum    = small_ + 16384;              // 16
    float* psumsq  = small_ + 16400;              // 16
    unsigned* phist = (unsigned*)(small_ + 16416);// 1024
    unsigned* mhist = (unsigned*)(small_ + 17440);// NBIN*16 = 32768 (region sized 65536)
    unsigned* ccnt  = (unsigned*)(small_ + 82976);// 16    (zeroed range ends at 82992)
    int* selbin    = (int*)(small_ + 82992);      // 16
    float* dom     = small_ + 83008;              // 2048
    float* comb    = small_ + 85056;              // 17456
    float* out1    = small_ + 102512;             // 8192
    _Float16* wrep = (_Float16*)(small_ + 110704);// 18432 f16 = 9216 dwords
    float2* twg    = (float2*)(small_ + 119920);  // 512 float2 = 1024 dwords
    float* cand    = small_ + 120944;             // 16*4096 = 65536 dwords
    float* zbuf    = cand;                        // alias (cand dead after sort)
    _Float16* w1r  = (_Float16*)(small_ + 186480);// 1024 f16 = 512 dwords

    init_kernel<<<325, 256, 0, stream>>>(sacc, twg, w2, w1, wrep, w1r);
    fft_rows<<<8192, 256, 0, stream>>>(img, twg, rowfft);
    fft_cols<<<1024, 256, 0, stream>>>(rowfft, twg, magT, psum, psumsq, phist, mhist);
    thresh_kernel<<<16, 256, 0, stream>>>(mhist, selbin);
    collect_kernel<<<256, 256, 0, stream>>>(magT, selbin, cand, ccnt);
    sort_kernel<<<16, 1024, 0, stream>>>(cand, ccnt, dom);
    sims_kernel<<<1, 256, 0, stream>>>(dom, rec, comb, out);
    grad_conv1_mfma<<<4096, 256, 0, stream>>>(img, (const half8*)w1r, c1b, h1);
    conv2_mfma<<<2048, 256, 0, stream>>>(h1, (const half8*)wrep, c2b, sacc);
    finalize_kernel<<<65, 256, 0, stream>>>(sacc, psum, psumsq, phist, comb, out);
    fc1_kernel<<<2048, 256, 0, stream>>>(comb, fw1, fb1, out1);
    fc2_kernel<<<512, 256, 0, stream>>>(out1, fw2, fb2, zbuf);
    ln_kernel<<<16, 128, 0, stream>>>(zbuf, lng, lnb, out);
}